// Round 10
// baseline (321.898 us; speedup 1.0000x reference)
//
#include <hip/hip_runtime.h>
#include <math.h>

#define NEG_SLOPE 0.2f
#define LOG2E 1.4426950408889634f

typedef __attribute__((ext_vector_type(8))) short short8;   // 8 bf16 (4 VGPRs)
typedef __attribute__((ext_vector_type(4))) float f32x4;

__device__ __forceinline__ int imin(int a, int b) { return a < b ? a : b; }

__device__ __forceinline__ unsigned int f2bf(float f) {
    unsigned int u = __float_as_uint(f);
    return (u + 0x7fffu + ((u >> 16) & 1u)) >> 16;   // RNE
}
__device__ __forceinline__ void bf2f(unsigned int u, float& a, float& b) {
    a = __uint_as_float(u << 16);
    b = __uint_as_float(u & 0xffff0000u);
}
template <int CTRL>
__device__ __forceinline__ float dpp_add(float v) {
    int t = __builtin_amdgcn_update_dpp(0, __float_as_int(v), CTRL, 0xF, 0xF, true);
    return v + __int_as_float(t);
}

// ---------------------------------------------------------------------------
// Kernel 1: packed histogram. One 64-bit atomic per edge onto a 64B-padded
// slot: low 32 = count, high 32 = ea sum in 2^-16 fixed point.
// ---------------------------------------------------------------------------
__global__ void edge_hist(const int* __restrict__ ei, const float* __restrict__ ea,
                          unsigned long long* __restrict__ hist, int E) {
    int e = blockIdx.x * blockDim.x + threadIdx.x;
    if (e < E) {
        int d = ei[E + e];
        long long fx = (long long)__float2int_rn(ea[e] * 65536.0f);
        unsigned long long v = ((unsigned long long)fx << 32) | 1ull;
        atomicAdd(&hist[(size_t)d * 8], v);
    }
}

// ---------------------------------------------------------------------------
// 3-phase parallel scan over hist (padded stride 8).
// ---------------------------------------------------------------------------
__global__ void scan_a(const unsigned long long* __restrict__ hist, int* __restrict__ bsum, int n) {
    __shared__ int wred[4];
    int base = blockIdx.x * 1024;
    int tid = threadIdx.x;
    int s = 0;
#pragma unroll
    for (int k = 0; k < 4; ++k) {
        int i = base + tid + k * 256;
        if (i < n) s += (int)(hist[(size_t)i * 8] & 0xffffffffull);
    }
#pragma unroll
    for (int off = 32; off > 0; off >>= 1) s += __shfl_xor(s, off, 64);
    if ((tid & 63) == 0) wred[tid >> 6] = s;
    __syncthreads();
    if (tid == 0) bsum[blockIdx.x] = wred[0] + wred[1] + wred[2] + wred[3];
}

__global__ void scan_b(int* __restrict__ bsum, int* __restrict__ row_ptr, int B, int n) {
    int tid = threadIdx.x;           // 64 threads, B <= 64
    int v = (tid < B) ? bsum[tid] : 0;
    int s = v;
#pragma unroll
    for (int off = 1; off < 64; off <<= 1) {
        int t = __shfl_up(s, off, 64);
        if (tid >= off) s += t;
    }
    if (tid < B) bsum[tid] = s - v;  // exclusive
    if (tid == 63) row_ptr[n] = s;   // total
}

__global__ void scan_c(const unsigned long long* __restrict__ hist,
                       const int* __restrict__ bsum, int* __restrict__ row_ptr,
                       int* __restrict__ wptr_pad, float* __restrict__ ea_loop, int n) {
    __shared__ int wtot[4];
    int tid = threadIdx.x;
    int wid = tid >> 6, lane = tid & 63;
    int i0 = blockIdx.x * 1024 + tid * 4;
    int dcnt[4]; float esum[4];
#pragma unroll
    for (int k = 0; k < 4; ++k) {
        if (i0 + k < n) {
            unsigned long long h = hist[(size_t)(i0 + k) * 8];
            dcnt[k] = (int)(h & 0xffffffffull);
            esum[k] = (float)((int)(h >> 32)) * (1.0f / 65536.0f);
        } else { dcnt[k] = 0; esum[k] = 0.0f; }
    }
    int tsum = dcnt[0] + dcnt[1] + dcnt[2] + dcnt[3];
    int s = tsum;
#pragma unroll
    for (int off = 1; off < 64; off <<= 1) {
        int t = __shfl_up(s, off, 64);
        if (lane >= off) s += t;
    }
    if (lane == 63) wtot[wid] = s;
    __syncthreads();
    int wpre = 0;
#pragma unroll
    for (int k = 0; k < 4; ++k) if (k < wid) wpre += wtot[k];
    int pre = bsum[blockIdx.x] + wpre + (s - tsum);
    if (i0 < n) {
        int4 e;
        e.x = pre;
        e.y = pre + dcnt[0];
        e.z = e.y + dcnt[1];
        e.w = e.z + dcnt[2];
        *(int4*)(row_ptr + i0) = e;
        int ev[4] = { e.x, e.y, e.z, e.w };
        float4 el;
        el.x = esum[0] / fmaxf((float)dcnt[0], 1.0f);
        el.y = esum[1] / fmaxf((float)dcnt[1], 1.0f);
        el.z = esum[2] / fmaxf((float)dcnt[2], 1.0f);
        el.w = esum[3] / fmaxf((float)dcnt[3], 1.0f);
        *(float4*)(ea_loop + i0) = el;
#pragma unroll
        for (int k = 0; k < 4; ++k) wptr_pad[(size_t)(i0 + k) * 16] = ev[k];
    }
}

// ---------------------------------------------------------------------------
// Kernel 3: scatter edges into CSR order; (src,w) packed as int2.
// ---------------------------------------------------------------------------
__global__ void edge_scatter(const int* __restrict__ ei, const float* __restrict__ ea,
                             int* __restrict__ wptr_pad, int2* __restrict__ spk, int E) {
    int e = blockIdx.x * blockDim.x + threadIdx.x;
    if (e < E) {
        int d = ei[E + e];
        int pos = atomicAdd(&wptr_pad[(size_t)d * 16], 1);
        spk[pos] = make_int2(ei[e], __float_as_int(ea[e]));
    }
}

// ---------------------------------------------------------------------------
// Conversion: x -> bf16 vec4
// ---------------------------------------------------------------------------
__global__ void cvt_bf16_v4(const float* __restrict__ in, unsigned short* __restrict__ out, int sz4) {
    int i = blockIdx.x * blockDim.x + threadIdx.x;
    if (i < sz4) {
        float4 v = ((const float4*)in)[i];
        uint2 r;
        r.x = f2bf(v.x) | (f2bf(v.y) << 16);
        r.y = f2bf(v.z) | (f2bf(v.w) << 16);
        ((uint2*)out)[i] = r;
    }
}

// ---------------------------------------------------------------------------
// Fused weight prep: 4 transposed bf16 conversions + 2 bias concats.
// ---------------------------------------------------------------------------
__global__ void prep_weights(const float* __restrict__ W1l, const float* __restrict__ W1r,
                             const float* __restrict__ W2l, const float* __restrict__ W2r,
                             const float* __restrict__ b1l, const float* __restrict__ b1r,
                             const float* __restrict__ b2l, const float* __restrict__ b2r,
                             unsigned short* __restrict__ Wt1, unsigned short* __restrict__ Wt2,
                             float* __restrict__ b1cat, float* __restrict__ b2cat,
                             int F, int HC1, int HC2) {
    int S1 = F * HC1, S2 = HC1 * HC2;
    int i = blockIdx.x * blockDim.x + threadIdx.x;
    if (i < S1) {
        int k = i / HC1, nn = i - k * HC1;
        Wt1[(size_t)nn * F + k] = (unsigned short)f2bf(W1l[i]);
    } else if (i < 2 * S1) {
        int j = i - S1;
        int k = j / HC1, nn = j - k * HC1;
        Wt1[(size_t)(HC1 + nn) * F + k] = (unsigned short)f2bf(W1r[j]);
    } else if (i < 2 * S1 + S2) {
        int j = i - 2 * S1;
        int k = j / HC2, nn = j - k * HC2;
        Wt2[(size_t)nn * HC1 + k] = (unsigned short)f2bf(W2l[j]);
    } else if (i < 2 * S1 + 2 * S2) {
        int j = i - 2 * S1 - S2;
        int k = j / HC2, nn = j - k * HC2;
        Wt2[(size_t)(HC2 + nn) * HC1 + k] = (unsigned short)f2bf(W2r[j]);
    } else if (i < 2 * S1 + 2 * S2 + 2 * HC1) {
        int j = i - 2 * S1 - 2 * S2;
        b1cat[j] = (j < HC1) ? b1l[j] : b1r[j - HC1];
    } else if (i < 2 * S1 + 2 * S2 + 2 * HC1 + 2 * HC2) {
        int j = i - 2 * S1 - 2 * S2 - 2 * HC1;
        b2cat[j] = (j < HC2) ? b2l[j] : b2r[j - HC2];
    }
}

// ---------------------------------------------------------------------------
// Kernel 4: bf16 MFMA GEMM + bias (B pre-transposed), 64x64 tile, BK=32.
// ---------------------------------------------------------------------------
__global__ void __launch_bounds__(256)
gemm_bf16(const unsigned short* __restrict__ A, const unsigned short* __restrict__ Bt,
          const float* __restrict__ bias, unsigned short* __restrict__ C,
          int M, int N, int K) {
    __shared__ __attribute__((aligned(16))) unsigned short As[64 * 40];
    __shared__ __attribute__((aligned(16))) unsigned short Bs[64 * 40];
    int tid  = threadIdx.x;
    int wave = tid >> 6, lane = tid & 63;
    int m0 = blockIdx.x * 64, n0 = blockIdx.y * 64;
    int row = tid >> 2, kg = (tid & 3) * 8;

    f32x4 acc[4] = {};
    for (int kk = 0; kk < K; kk += 32) {
        int gm = m0 + row;
        uint4 av;
        if (gm < M) av = *(const uint4*)(A + (size_t)gm * K + kk + kg);
        else        av = make_uint4(0, 0, 0, 0);
        *(uint4*)&As[row * 40 + kg] = av;
        uint4 bv = *(const uint4*)(Bt + (size_t)(n0 + row) * K + kk + kg);
        *(uint4*)&Bs[row * 40 + kg] = bv;
        __syncthreads();
        short8 a = *(const short8*)&As[(wave * 16 + (lane & 15)) * 40 + (lane >> 4) * 8];
#pragma unroll
        for (int g = 0; g < 4; ++g) {
            short8 b = *(const short8*)&Bs[(g * 16 + (lane & 15)) * 40 + (lane >> 4) * 8];
            acc[g] = __builtin_amdgcn_mfma_f32_16x16x32_bf16(a, b, acc[g], 0, 0, 0);
        }
        __syncthreads();
    }
#pragma unroll
    for (int g = 0; g < 4; ++g) {
        int col = n0 + g * 16 + (lane & 15);
        float bs = bias[col];
#pragma unroll
        for (int r = 0; r < 4; ++r) {
            int grow = m0 + wave * 16 + (lane >> 4) * 4 + r;
            if (grow < M) C[(size_t)grow * N + col] = (unsigned short)f2bf(acc[g][r] + bs);
        }
    }
}

// ---------------------------------------------------------------------------
// helpers for gat_agg
// ---------------------------------------------------------------------------
template <int NV>
__device__ __forceinline__ void ld_row(float* r, const float* p) {
    if constexpr (NV == 4) {
        float4 t = *(const float4*)p;
        r[0] = t.x; r[1] = t.y; r[2] = t.z; r[3] = t.w;
    } else {
        float2 t = *(const float2*)p;
        r[0] = t.x; r[1] = t.y;
    }
}
template <int NV>
__device__ __forceinline__ uint2 ld_bf(const unsigned short* __restrict__ base, int laneoff) {
    uint2 r;
    if constexpr (NV == 4) r = *(const uint2*)(base + laneoff);
    else { r.x = *(const unsigned int*)(base + laneoff); r.y = 0; }
    return r;
}
template <int G>
__device__ __forceinline__ float grp_reduce(float vs) {
    vs = dpp_add<0xB1>(vs);              // xor 1
    vs = dpp_add<0x4E>(vs);              // xor 2
    vs = dpp_add<0x141>(vs);             // xor 4 (row_half_mirror)
    if constexpr (G >= 16) vs = dpp_add<0x140>(vs);   // xor 8 (row_mirror)
    if constexpr (G >= 32) {             // xor 16
        int t = __builtin_amdgcn_ds_swizzle(__float_as_int(vs), 0x401F);
        vs += __int_as_float(t);
    }
    if constexpr (G >= 64) vs += __shfl_xor(vs, 32, 64);
    return vs;
}

// ---------------------------------------------------------------------------
// Kernel 5: fused GATv2 gather(bf16) + score + softmax + aggregate + relu.
// Scalar fp32 channel math (pk-f32 gives no cycle gain on 32-wide SIMD).
// att coefficients pre-scaled by log2e so pr = exp2(vs) (saves v_mul/edge).
// Unroll-8 edge pipeline: 8 gather slots in flight per wave.
// ---------------------------------------------------------------------------
template <int HC, int STRIDE, int C, bool OUT_BF16>
__global__ void __launch_bounds__(256)
gat_agg(const unsigned short* __restrict__ xlr,
        const float* __restrict__ We, const float* __restrict__ att,
        const float* __restrict__ bias,
        const int* __restrict__ row_ptr, const int2* __restrict__ spk,
        const float* __restrict__ ea_loop,
        void* __restrict__ out, int n) {
    constexpr int NV = HC / 64;      // channels per lane
    constexpr int G  = C / NV;       // lanes per head
    int wave = threadIdx.x >> 6;
    int lane = threadIdx.x & 63;
    int node = blockIdx.x * 4 + wave;
    if (node >= n) return;
    int laneoff = lane * NV;

    float xr_r[NV], We_r[NV], att6[NV], att4[NV], o[NV];
    {
        uint2 u = ld_bf<NV>(xlr + (size_t)node * STRIDE + HC, laneoff);
        bf2f(u.x, xr_r[0], xr_r[1]);
        if constexpr (NV == 4) bf2f(u.y, xr_r[2], xr_r[3]);
    }
    ld_row<NV>(We_r, We + laneoff);
    {
        float att_r[NV];
        ld_row<NV>(att_r, att + laneoff);
#pragma unroll
        for (int j = 0; j < NV; ++j) {
            att6[j] = 0.6f * LOG2E * att_r[j];
            att4[j] = 0.4f * LOG2E * att_r[j];
        }
    }
#pragma unroll
    for (int j = 0; j < NV; ++j) o[j] = 0.0f;

    int start = __builtin_amdgcn_readfirstlane(row_ptr[node]);
    int end   = __builtin_amdgcn_readfirstlane(row_ptr[node + 1]);
    float ea_l = ea_loop[node];
    float l = 0.0f;

    auto process = [&](uint2 xu, float w) {
        float xf[NV];
        bf2f(xu.x, xf[0], xf[1]);
        if constexpr (NV == 4) bf2f(xu.y, xf[2], xf[3]);
        float vs = 0.0f;
#pragma unroll
        for (int j = 0; j < NV; ++j) {
            float mm = xf[j] + fmaf(w, We_r[j], xr_r[j]);
            vs = fmaf(att6[j], mm, vs);
            vs = fmaf(att4[j], fabsf(mm), vs);
        }
        vs = grp_reduce<G>(vs);
        float pr = exp2f(vs);
        l += pr;
#pragma unroll
        for (int j = 0; j < NV; ++j) o[j] = fmaf(pr, xf[j], o[j]);
    };

    // ---- self-loop edge ----
    process(ld_bf<NV>(xlr + (size_t)node * STRIDE, laneoff), ea_l);

    // ---- real edges, batches of 64, unroll-8 with 8 slots in flight ----
    int cnt = end - start;
    for (int b0 = 0; b0 < cnt; b0 += 64) {
        int rem = imin(64, cnt - b0);
        int idx = start + b0 + lane;
        int idxc = imin(idx, end - 1);
        int2 pv = spk[idxc];

        auto rl = [&](int j) {
            int s = __builtin_amdgcn_readlane(pv.x, j);
            return ld_bf<NV>(xlr + (size_t)s * STRIDE, laneoff);
        };
        auto rw = [&](int j) {
            return __int_as_float(__builtin_amdgcn_readlane(pv.y, j));
        };

        int rc = rem - 1;
        uint2 X[8]; float Wv[8];
#pragma unroll
        for (int k = 0; k < 8; ++k) {
            int t = imin(k, rc);
            X[k] = rl(t); Wv[k] = rw(t);
        }

        int j = 0;
        for (; j + 8 <= rem; j += 8) {
            uint2 Y[8]; float U[8];
#pragma unroll
            for (int k = 0; k < 8; ++k) {
                int t = imin(j + 8 + k, rc);
                Y[k] = rl(t); U[k] = rw(t);
            }
#pragma unroll
            for (int k = 0; k < 8; ++k) process(X[k], Wv[k]);
#pragma unroll
            for (int k = 0; k < 8; ++k) { X[k] = Y[k]; Wv[k] = U[k]; }
        }
#pragma unroll
        for (int k = 0; k < 8; ++k) {
            if (j + k < rem) process(X[k], Wv[k]);
        }
    }

    float inv = 1.0f / (l + 1e-16f);
    float b_r[NV];
    ld_row<NV>(b_r, bias + laneoff);
    float v[NV];
#pragma unroll
    for (int j = 0; j < NV; ++j) v[j] = fmaxf(o[j] * inv + b_r[j], 0.0f);

    if constexpr (OUT_BF16) {
        unsigned short* op = (unsigned short*)out + (size_t)node * HC + laneoff;
        if constexpr (NV == 4) {
            uint2 t;
            t.x = f2bf(v[0]) | (f2bf(v[1]) << 16);
            t.y = f2bf(v[2]) | (f2bf(v[3]) << 16);
            *(uint2*)op = t;
        } else {
            *(unsigned int*)op = f2bf(v[0]) | (f2bf(v[1]) << 16);
        }
    } else {
        float* op = (float*)out + (size_t)node * HC + laneoff;
        if constexpr (NV == 4) { *(float4*)op = make_float4(v[0], v[1], v[2], v[3]); }
        else                   { *(float2*)op = make_float2(v[0], v[1]); }
    }
}

// ---------------------------------------------------------------------------
// Kernel 6: column partial sums of h2 [n,128] -> partial[gridDim.x*128]
// ---------------------------------------------------------------------------
__global__ void pool_partial(const float* __restrict__ h2, float* __restrict__ partial, int n) {
    int t = threadIdx.x;
    float s = 0.0f;
    for (int r = blockIdx.x; r < n; r += gridDim.x) s += h2[(size_t)r * 128 + t];
    partial[blockIdx.x * 128 + t] = s;
}

// ---------------------------------------------------------------------------
// Kernel 7: finish pooling, softmax over 128, sigmoid(alpha). 1024 threads.
// ---------------------------------------------------------------------------
__global__ void __launch_bounds__(1024)
pool_final(const float* __restrict__ partial, int nb,
           const float* __restrict__ alpha_in,
           float* __restrict__ out, int n) {
    __shared__ float acc[8][128];
    __shared__ float red[4];
    int t = threadIdx.x & 127;        // column
    int g = threadIdx.x >> 7;         // group 0..7
    float s = 0.0f;
    for (int b = g; b < nb; b += 8) s += partial[b * 128 + t];
    acc[g][t] = s;
    __syncthreads();
    if (threadIdx.x < 128) {
        float tot = 0.0f;
#pragma unroll
        for (int k = 0; k < 8; ++k) tot += acc[k][t];
        float mean = tot / (float)n;
        float mx = mean;
#pragma unroll
        for (int off = 32; off > 0; off >>= 1) mx = fmaxf(mx, __shfl_xor(mx, off, 64));
        if ((t & 63) == 0) red[t >> 6] = mx;
        __syncthreads();
        mx = fmaxf(red[0], red[1]);
        float ex = __expf(mean - mx);
        float sm = ex;
#pragma unroll
        for (int off = 32; off > 0; off >>= 1) sm += __shfl_xor(sm, off, 64);
        if ((t & 63) == 0) red[2 + (t >> 6)] = sm;
        __syncthreads();
        sm = red[2] + red[3];
        out[t] = ex / sm;
        if (t == 0) out[128] = 1.0f / (1.0f + __expf(-alpha_in[0]));
    }
}

// ---------------------------------------------------------------------------
extern "C" void kernel_launch(void* const* d_in, const int* in_sizes, int n_in,
                              void* d_out, int out_size, void* d_ws, size_t ws_size,
                              hipStream_t stream) {
    const float* x    = (const float*)d_in[0];
    const int*   ei   = (const int*)d_in[1];
    const float* ea   = (const float*)d_in[2];
    const float* W1l  = (const float*)d_in[3];
    const float* b1l  = (const float*)d_in[4];
    const float* W1r  = (const float*)d_in[5];
    const float* b1r  = (const float*)d_in[6];
    const float* We1  = (const float*)d_in[7];
    const float* att1 = (const float*)d_in[8];
    const float* bias1= (const float*)d_in[9];
    const float* W2l  = (const float*)d_in[10];
    const float* b2l  = (const float*)d_in[11];
    const float* W2r  = (const float*)d_in[12];
    const float* b2r  = (const float*)d_in[13];
    const float* We2  = (const float*)d_in[14];
    const float* att2 = (const float*)d_in[15];
    const float* bias2= (const float*)d_in[16];
    const float* alpha= (const float*)d_in[17];
    float* out = (float*)d_out;

    const int F = 128, HC1 = 256, HC2 = 128;
    const int n = in_sizes[0] / F;       // 20000
    const int E = in_sizes[1] / 2;       // 640000
    const int B = (n + 1023) / 1024;     // scan blocks

    char* ws = (char*)d_ws;
    size_t off = 0;
    auto alloc = [&](size_t bytes) { size_t p = off; off += (bytes + 255) & ~(size_t)255; return p; };

    unsigned long long* hist = (unsigned long long*)(ws + alloc((size_t)n * 8 * 8));  // padded x8
    int*   row_ptr = (int*)  (ws + alloc((size_t)(n + 1) * 4));
    int*   wptr    = (int*)  (ws + alloc((size_t)n * 16 * 4));                        // padded x16
    float* ea_loop = (float*)(ws + alloc((size_t)n * 4));
    int*   bsum    = (int*)  (ws + alloc(64 * 4));
    int2*  spk     = (int2*) (ws + alloc((size_t)E * 8));
    unsigned short* xb   = (unsigned short*)(ws + alloc((size_t)n * F * 2));
    unsigned short* Wt1  = (unsigned short*)(ws + alloc((size_t)F * (2 * HC1) * 2));
    unsigned short* Wt2  = (unsigned short*)(ws + alloc((size_t)HC1 * (2 * HC2) * 2));
    float* b1cat   = (float*)(ws + alloc((size_t)2 * HC1 * 4));
    float* b2cat   = (float*)(ws + alloc((size_t)2 * HC2 * 4));
    unsigned short* xlr1 = (unsigned short*)(ws + alloc((size_t)n * 2 * HC1 * 2));
    unsigned short* h1   = (unsigned short*)(ws + alloc((size_t)n * HC1 * 2));
    float* h2      = (float*)(ws + alloc((size_t)n * HC2 * 4));
    float* partial = (float*)(ws + alloc((size_t)256 * 128 * 4));
    unsigned short* xlr2 = xlr1;   // layer-2 projections alias layer-1 buffer
    const int NB_POOL = 256;

    (void)hipMemsetAsync(hist, 0, (size_t)n * 8 * 8, stream);

    int tb = 256;
    edge_hist<<<(E + tb - 1) / tb, tb, 0, stream>>>(ei, ea, hist, E);
    scan_a<<<B, 256, 0, stream>>>(hist, bsum, n);
    scan_b<<<1, 64, 0, stream>>>(bsum, row_ptr, B, n);
    scan_c<<<B, 256, 0, stream>>>(hist, bsum, row_ptr, wptr, ea_loop, n);
    edge_scatter<<<(E + tb - 1) / tb, tb, 0, stream>>>(ei, ea, wptr, spk, E);

    cvt_bf16_v4<<<(n * F / 4 + tb - 1) / tb, tb, 0, stream>>>(x, xb, n * F / 4);
    {
        int total = 2 * F * HC1 + 2 * HC1 * HC2 + 2 * HC1 + 2 * HC2;
        prep_weights<<<(total + tb - 1) / tb, tb, 0, stream>>>(
            W1l, W1r, W2l, W2r, b1l, b1r, b2l, b2r, Wt1, Wt2, b1cat, b2cat, F, HC1, HC2);
    }

    // layer 1: one merged GEMM [n,128]@[128,512] -> xlr1 (xl | xr rows)
    {
        dim3 grid((n + 63) / 64, (2 * HC1) / 64);
        gemm_bf16<<<grid, 256, 0, stream>>>(xb, Wt1, b1cat, xlr1, n, 2 * HC1, F);
    }
    gat_agg<256, 512, 32, true><<<(n + 3) / 4, 256, 0, stream>>>(
        xlr1, We1, att1, bias1, row_ptr, spk, ea_loop, h1, n);

    // layer 2: one merged GEMM [n,256]@[256,256] -> xlr2
    {
        dim3 grid((n + 63) / 64, (2 * HC2) / 64);
        gemm_bf16<<<grid, 256, 0, stream>>>(h1, Wt2, b2cat, xlr2, n, 2 * HC2, HC1);
    }
    gat_agg<128, 256, 128, false><<<(n + 3) / 4, 256, 0, stream>>>(
        xlr2, We2, att2, bias2, row_ptr, spk, ea_loop, h2, n);

    pool_partial<<<NB_POOL, 128, 0, stream>>>(h2, partial, n);
    pool_final<<<1, 1024, 0, stream>>>(partial, NB_POOL, alpha, out, n);
}

// Round 12
// 312.440 us; speedup vs baseline: 1.0303x; 1.0303x over previous
//
#include <hip/hip_runtime.h>
#include <math.h>

#define NEG_SLOPE 0.2f
#define LOG2E 1.4426950408889634f

typedef __attribute__((ext_vector_type(8))) short short8;   // 8 bf16 (4 VGPRs)
typedef __attribute__((ext_vector_type(4))) float f32x4;

__device__ __forceinline__ int imin(int a, int b) { return a < b ? a : b; }

__device__ __forceinline__ unsigned int f2bf(float f) {
    unsigned int u = __float_as_uint(f);
    return (u + 0x7fffu + ((u >> 16) & 1u)) >> 16;   // RNE
}
__device__ __forceinline__ void bf2f(unsigned int u, float& a, float& b) {
    a = __uint_as_float(u << 16);
    b = __uint_as_float(u & 0xffff0000u);
}
template <int CTRL>
__device__ __forceinline__ float dpp_add(float v) {
    int t = __builtin_amdgcn_update_dpp(0, __float_as_int(v), CTRL, 0xF, 0xF, true);
    return v + __int_as_float(t);
}

// ---------------------------------------------------------------------------
// Kernel 1: packed histogram. One 64-bit atomic per edge onto a 64B-padded
// slot: low 32 = count, high 32 = ea sum in 2^-16 fixed point.
// ---------------------------------------------------------------------------
__global__ void edge_hist(const int* __restrict__ ei, const float* __restrict__ ea,
                          unsigned long long* __restrict__ hist, int E) {
    int e = blockIdx.x * blockDim.x + threadIdx.x;
    if (e < E) {
        int d = ei[E + e];
        long long fx = (long long)__float2int_rn(ea[e] * 65536.0f);
        unsigned long long v = ((unsigned long long)fx << 32) | 1ull;
        atomicAdd(&hist[(size_t)d * 8], v);
    }
}

// ---------------------------------------------------------------------------
// 3-phase parallel scan over hist (padded stride 8).
// ---------------------------------------------------------------------------
__global__ void scan_a(const unsigned long long* __restrict__ hist, int* __restrict__ bsum, int n) {
    __shared__ int wred[4];
    int base = blockIdx.x * 1024;
    int tid = threadIdx.x;
    int s = 0;
#pragma unroll
    for (int k = 0; k < 4; ++k) {
        int i = base + tid + k * 256;
        if (i < n) s += (int)(hist[(size_t)i * 8] & 0xffffffffull);
    }
#pragma unroll
    for (int off = 32; off > 0; off >>= 1) s += __shfl_xor(s, off, 64);
    if ((tid & 63) == 0) wred[tid >> 6] = s;
    __syncthreads();
    if (tid == 0) bsum[blockIdx.x] = wred[0] + wred[1] + wred[2] + wred[3];
}

__global__ void scan_b(int* __restrict__ bsum, int* __restrict__ row_ptr, int B, int n) {
    int tid = threadIdx.x;           // 64 threads, B <= 64
    int v = (tid < B) ? bsum[tid] : 0;
    int s = v;
#pragma unroll
    for (int off = 1; off < 64; off <<= 1) {
        int t = __shfl_up(s, off, 64);
        if (tid >= off) s += t;
    }
    if (tid < B) bsum[tid] = s - v;  // exclusive
    if (tid == 63) row_ptr[n] = s;   // total
}

__global__ void scan_c(const unsigned long long* __restrict__ hist,
                       const int* __restrict__ bsum, int* __restrict__ row_ptr,
                       int* __restrict__ wptr_pad, float* __restrict__ ea_loop, int n) {
    __shared__ int wtot[4];
    int tid = threadIdx.x;
    int wid = tid >> 6, lane = tid & 63;
    int i0 = blockIdx.x * 1024 + tid * 4;
    int dcnt[4]; float esum[4];
#pragma unroll
    for (int k = 0; k < 4; ++k) {
        if (i0 + k < n) {
            unsigned long long h = hist[(size_t)(i0 + k) * 8];
            dcnt[k] = (int)(h & 0xffffffffull);
            esum[k] = (float)((int)(h >> 32)) * (1.0f / 65536.0f);
        } else { dcnt[k] = 0; esum[k] = 0.0f; }
    }
    int tsum = dcnt[0] + dcnt[1] + dcnt[2] + dcnt[3];
    int s = tsum;
#pragma unroll
    for (int off = 1; off < 64; off <<= 1) {
        int t = __shfl_up(s, off, 64);
        if (lane >= off) s += t;
    }
    if (lane == 63) wtot[wid] = s;
    __syncthreads();
    int wpre = 0;
#pragma unroll
    for (int k = 0; k < 4; ++k) if (k < wid) wpre += wtot[k];
    int pre = bsum[blockIdx.x] + wpre + (s - tsum);
    if (i0 < n) {
        int4 e;
        e.x = pre;
        e.y = pre + dcnt[0];
        e.z = e.y + dcnt[1];
        e.w = e.z + dcnt[2];
        *(int4*)(row_ptr + i0) = e;
        int ev[4] = { e.x, e.y, e.z, e.w };
        float4 el;
        el.x = esum[0] / fmaxf((float)dcnt[0], 1.0f);
        el.y = esum[1] / fmaxf((float)dcnt[1], 1.0f);
        el.z = esum[2] / fmaxf((float)dcnt[2], 1.0f);
        el.w = esum[3] / fmaxf((float)dcnt[3], 1.0f);
        *(float4*)(ea_loop + i0) = el;
#pragma unroll
        for (int k = 0; k < 4; ++k) wptr_pad[(size_t)(i0 + k) * 16] = ev[k];
    }
}

// ---------------------------------------------------------------------------
// Kernel 3: scatter edges into CSR order; (src,w) packed as int2.
// ---------------------------------------------------------------------------
__global__ void edge_scatter(const int* __restrict__ ei, const float* __restrict__ ea,
                             int* __restrict__ wptr_pad, int2* __restrict__ spk, int E) {
    int e = blockIdx.x * blockDim.x + threadIdx.x;
    if (e < E) {
        int d = ei[E + e];
        int pos = atomicAdd(&wptr_pad[(size_t)d * 16], 1);
        spk[pos] = make_int2(ei[e], __float_as_int(ea[e]));
    }
}

// ---------------------------------------------------------------------------
// Conversion: x -> bf16 vec4
// ---------------------------------------------------------------------------
__global__ void cvt_bf16_v4(const float* __restrict__ in, unsigned short* __restrict__ out, int sz4) {
    int i = blockIdx.x * blockDim.x + threadIdx.x;
    if (i < sz4) {
        float4 v = ((const float4*)in)[i];
        uint2 r;
        r.x = f2bf(v.x) | (f2bf(v.y) << 16);
        r.y = f2bf(v.z) | (f2bf(v.w) << 16);
        ((uint2*)out)[i] = r;
    }
}

// ---------------------------------------------------------------------------
// Fused weight prep: 4 transposed bf16 conversions + 2 bias concats.
// ---------------------------------------------------------------------------
__global__ void prep_weights(const float* __restrict__ W1l, const float* __restrict__ W1r,
                             const float* __restrict__ W2l, const float* __restrict__ W2r,
                             const float* __restrict__ b1l, const float* __restrict__ b1r,
                             const float* __restrict__ b2l, const float* __restrict__ b2r,
                             unsigned short* __restrict__ Wt1, unsigned short* __restrict__ Wt2,
                             float* __restrict__ b1cat, float* __restrict__ b2cat,
                             int F, int HC1, int HC2) {
    int S1 = F * HC1, S2 = HC1 * HC2;
    int i = blockIdx.x * blockDim.x + threadIdx.x;
    if (i < S1) {
        int k = i / HC1, nn = i - k * HC1;
        Wt1[(size_t)nn * F + k] = (unsigned short)f2bf(W1l[i]);
    } else if (i < 2 * S1) {
        int j = i - S1;
        int k = j / HC1, nn = j - k * HC1;
        Wt1[(size_t)(HC1 + nn) * F + k] = (unsigned short)f2bf(W1r[j]);
    } else if (i < 2 * S1 + S2) {
        int j = i - 2 * S1;
        int k = j / HC2, nn = j - k * HC2;
        Wt2[(size_t)nn * HC1 + k] = (unsigned short)f2bf(W2l[j]);
    } else if (i < 2 * S1 + 2 * S2) {
        int j = i - 2 * S1 - S2;
        int k = j / HC2, nn = j - k * HC2;
        Wt2[(size_t)(HC2 + nn) * HC1 + k] = (unsigned short)f2bf(W2r[j]);
    } else if (i < 2 * S1 + 2 * S2 + 2 * HC1) {
        int j = i - 2 * S1 - 2 * S2;
        b1cat[j] = (j < HC1) ? b1l[j] : b1r[j - HC1];
    } else if (i < 2 * S1 + 2 * S2 + 2 * HC1 + 2 * HC2) {
        int j = i - 2 * S1 - 2 * S2 - 2 * HC1;
        b2cat[j] = (j < HC2) ? b2l[j] : b2r[j - HC2];
    }
}

// ---------------------------------------------------------------------------
// Kernel 4: bf16 MFMA GEMM + bias (B pre-transposed), 64x64 tile, BK=32.
// ---------------------------------------------------------------------------
__global__ void __launch_bounds__(256)
gemm_bf16(const unsigned short* __restrict__ A, const unsigned short* __restrict__ Bt,
          const float* __restrict__ bias, unsigned short* __restrict__ C,
          int M, int N, int K) {
    __shared__ __attribute__((aligned(16))) unsigned short As[64 * 40];
    __shared__ __attribute__((aligned(16))) unsigned short Bs[64 * 40];
    int tid  = threadIdx.x;
    int wave = tid >> 6, lane = tid & 63;
    int m0 = blockIdx.x * 64, n0 = blockIdx.y * 64;
    int row = tid >> 2, kg = (tid & 3) * 8;

    f32x4 acc[4] = {};
    for (int kk = 0; kk < K; kk += 32) {
        int gm = m0 + row;
        uint4 av;
        if (gm < M) av = *(const uint4*)(A + (size_t)gm * K + kk + kg);
        else        av = make_uint4(0, 0, 0, 0);
        *(uint4*)&As[row * 40 + kg] = av;
        uint4 bv = *(const uint4*)(Bt + (size_t)(n0 + row) * K + kk + kg);
        *(uint4*)&Bs[row * 40 + kg] = bv;
        __syncthreads();
        short8 a = *(const short8*)&As[(wave * 16 + (lane & 15)) * 40 + (lane >> 4) * 8];
#pragma unroll
        for (int g = 0; g < 4; ++g) {
            short8 b = *(const short8*)&Bs[(g * 16 + (lane & 15)) * 40 + (lane >> 4) * 8];
            acc[g] = __builtin_amdgcn_mfma_f32_16x16x32_bf16(a, b, acc[g], 0, 0, 0);
        }
        __syncthreads();
    }
#pragma unroll
    for (int g = 0; g < 4; ++g) {
        int col = n0 + g * 16 + (lane & 15);
        float bs = bias[col];
#pragma unroll
        for (int r = 0; r < 4; ++r) {
            int grow = m0 + wave * 16 + (lane >> 4) * 4 + r;
            if (grow < M) C[(size_t)grow * N + col] = (unsigned short)f2bf(acc[g][r] + bs);
        }
    }
}

// ---------------------------------------------------------------------------
// helpers for gat_agg
// ---------------------------------------------------------------------------
template <int NV>
__device__ __forceinline__ void ld_row(float* r, const float* p) {
    if constexpr (NV == 4) {
        float4 t = *(const float4*)p;
        r[0] = t.x; r[1] = t.y; r[2] = t.z; r[3] = t.w;
    } else {
        float2 t = *(const float2*)p;
        r[0] = t.x; r[1] = t.y;
    }
}
template <int NV>
__device__ __forceinline__ uint2 ld_bf(const unsigned short* __restrict__ base, int laneoff) {
    uint2 r;
    if constexpr (NV == 4) r = *(const uint2*)(base + laneoff);
    else { r.x = *(const unsigned int*)(base + laneoff); r.y = 0; }
    return r;
}
template <int G>
__device__ __forceinline__ float grp_reduce(float vs) {
    vs = dpp_add<0xB1>(vs);              // xor 1
    vs = dpp_add<0x4E>(vs);              // xor 2
    vs = dpp_add<0x141>(vs);             // xor 4 (row_half_mirror)
    if constexpr (G >= 16) vs = dpp_add<0x140>(vs);   // xor 8 (row_mirror)
    if constexpr (G >= 32) {             // xor 16
        int t = __builtin_amdgcn_ds_swizzle(__float_as_int(vs), 0x401F);
        vs += __int_as_float(t);
    }
    if constexpr (G >= 64) vs += __shfl_xor(vs, 32, 64);
    return vs;
}

// ---------------------------------------------------------------------------
// Kernel 5: fused GATv2 gather(bf16) + score + softmax + aggregate + relu.
// R7-proven config: unroll-4 edge pipeline (4 gather slots, ~32 VGPR,
// occupancy ~55%).  att coefficients pre-scaled by log2e so pr = exp2(vs).
// ---------------------------------------------------------------------------
template <int HC, int STRIDE, int C, bool OUT_BF16>
__global__ void __launch_bounds__(256)
gat_agg(const unsigned short* __restrict__ xlr,
        const float* __restrict__ We, const float* __restrict__ att,
        const float* __restrict__ bias,
        const int* __restrict__ row_ptr, const int2* __restrict__ spk,
        const float* __restrict__ ea_loop,
        void* __restrict__ out, int n) {
    constexpr int NV = HC / 64;      // channels per lane
    constexpr int G  = C / NV;       // lanes per head
    int wave = threadIdx.x >> 6;
    int lane = threadIdx.x & 63;
    int node = blockIdx.x * 4 + wave;
    if (node >= n) return;
    int laneoff = lane * NV;

    float xr_r[NV], We_r[NV], att6[NV], att4[NV], o[NV];
    {
        uint2 u = ld_bf<NV>(xlr + (size_t)node * STRIDE + HC, laneoff);
        bf2f(u.x, xr_r[0], xr_r[1]);
        if constexpr (NV == 4) bf2f(u.y, xr_r[2], xr_r[3]);
    }
    ld_row<NV>(We_r, We + laneoff);
    {
        float att_r[NV];
        ld_row<NV>(att_r, att + laneoff);
#pragma unroll
        for (int j = 0; j < NV; ++j) {
            att6[j] = 0.6f * LOG2E * att_r[j];
            att4[j] = 0.4f * LOG2E * att_r[j];
        }
    }
#pragma unroll
    for (int j = 0; j < NV; ++j) o[j] = 0.0f;

    int start = __builtin_amdgcn_readfirstlane(row_ptr[node]);
    int end   = __builtin_amdgcn_readfirstlane(row_ptr[node + 1]);
    float ea_l = ea_loop[node];
    float l = 0.0f;

    auto process = [&](uint2 xu, float w) {
        float xf[NV];
        bf2f(xu.x, xf[0], xf[1]);
        if constexpr (NV == 4) bf2f(xu.y, xf[2], xf[3]);
        float vs = 0.0f;
#pragma unroll
        for (int j = 0; j < NV; ++j) {
            float mm = xf[j] + fmaf(w, We_r[j], xr_r[j]);
            vs = fmaf(att6[j], mm, vs);
            vs = fmaf(att4[j], fabsf(mm), vs);
        }
        vs = grp_reduce<G>(vs);
        float pr = exp2f(vs);
        l += pr;
#pragma unroll
        for (int j = 0; j < NV; ++j) o[j] = fmaf(pr, xf[j], o[j]);
    };

    // ---- self-loop edge ----
    process(ld_bf<NV>(xlr + (size_t)node * STRIDE, laneoff), ea_l);

    // ---- real edges, batches of 64, unroll-4 with 4 slots in flight ----
    int cnt = end - start;
    for (int b0 = 0; b0 < cnt; b0 += 64) {
        int rem = imin(64, cnt - b0);
        int idx = start + b0 + lane;
        int idxc = imin(idx, end - 1);
        int2 pv = spk[idxc];

        auto rl = [&](int j) {
            int s = __builtin_amdgcn_readlane(pv.x, j);
            return ld_bf<NV>(xlr + (size_t)s * STRIDE, laneoff);
        };
        auto rw = [&](int j) {
            return __int_as_float(__builtin_amdgcn_readlane(pv.y, j));
        };

        int rc = rem - 1;
        uint2 X0 = rl(0),            X1 = rl(imin(1, rc)),
              X2 = rl(imin(2, rc)),  X3 = rl(imin(3, rc));
        float W0 = rw(0),            W1 = rw(imin(1, rc)),
              W2 = rw(imin(2, rc)),  W3 = rw(imin(3, rc));

        int j = 0;
        for (; j + 4 <= rem; j += 4) {
            uint2 Y0 = rl(imin(j + 4, rc)), Y1 = rl(imin(j + 5, rc)),
                  Y2 = rl(imin(j + 6, rc)), Y3 = rl(imin(j + 7, rc));
            float U0 = rw(imin(j + 4, rc)), U1 = rw(imin(j + 5, rc)),
                  U2 = rw(imin(j + 6, rc)), U3 = rw(imin(j + 7, rc));
            process(X0, W0); process(X1, W1); process(X2, W2); process(X3, W3);
            X0 = Y0; X1 = Y1; X2 = Y2; X3 = Y3;
            W0 = U0; W1 = U1; W2 = U2; W3 = U3;
        }
        if (j < rem) {
            process(X0, W0);
            if (j + 1 < rem) {
                process(X1, W1);
                if (j + 2 < rem) process(X2, W2);
            }
        }
    }

    float inv = 1.0f / (l + 1e-16f);
    float b_r[NV];
    ld_row<NV>(b_r, bias + laneoff);
    float v[NV];
#pragma unroll
    for (int j = 0; j < NV; ++j) v[j] = fmaxf(o[j] * inv + b_r[j], 0.0f);

    if constexpr (OUT_BF16) {
        unsigned short* op = (unsigned short*)out + (size_t)node * HC + laneoff;
        if constexpr (NV == 4) {
            uint2 t;
            t.x = f2bf(v[0]) | (f2bf(v[1]) << 16);
            t.y = f2bf(v[2]) | (f2bf(v[3]) << 16);
            *(uint2*)op = t;
        } else {
            *(unsigned int*)op = f2bf(v[0]) | (f2bf(v[1]) << 16);
        }
    } else {
        float* op = (float*)out + (size_t)node * HC + laneoff;
        if constexpr (NV == 4) { *(float4*)op = make_float4(v[0], v[1], v[2], v[3]); }
        else                   { *(float2*)op = make_float2(v[0], v[1]); }
    }
}

// ---------------------------------------------------------------------------
// Kernel 6: column partial sums of h2 [n,128] -> partial[gridDim.x*128]
// ---------------------------------------------------------------------------
__global__ void pool_partial(const float* __restrict__ h2, float* __restrict__ partial, int n) {
    int t = threadIdx.x;
    float s = 0.0f;
    for (int r = blockIdx.x; r < n; r += gridDim.x) s += h2[(size_t)r * 128 + t];
    partial[blockIdx.x * 128 + t] = s;
}

// ---------------------------------------------------------------------------
// Kernel 7: finish pooling, softmax over 128, sigmoid(alpha). 1024 threads.
// ---------------------------------------------------------------------------
__global__ void __launch_bounds__(1024)
pool_final(const float* __restrict__ partial, int nb,
           const float* __restrict__ alpha_in,
           float* __restrict__ out, int n) {
    __shared__ float acc[8][128];
    __shared__ float red[4];
    int t = threadIdx.x & 127;        // column
    int g = threadIdx.x >> 7;         // group 0..7
    float s = 0.0f;
    for (int b = g; b < nb; b += 8) s += partial[b * 128 + t];
    acc[g][t] = s;
    __syncthreads();
    if (threadIdx.x < 128) {
        float tot = 0.0f;
#pragma unroll
        for (int k = 0; k < 8; ++k) tot += acc[k][t];
        float mean = tot / (float)n;
        float mx = mean;
#pragma unroll
        for (int off = 32; off > 0; off >>= 1) mx = fmaxf(mx, __shfl_xor(mx, off, 64));
        if ((t & 63) == 0) red[t >> 6] = mx;
        __syncthreads();
        mx = fmaxf(red[0], red[1]);
        float ex = __expf(mean - mx);
        float sm = ex;
#pragma unroll
        for (int off = 32; off > 0; off >>= 1) sm += __shfl_xor(sm, off, 64);
        if ((t & 63) == 0) red[2 + (t >> 6)] = sm;
        __syncthreads();
        sm = red[2] + red[3];
        out[t] = ex / sm;
        if (t == 0) out[128] = 1.0f / (1.0f + __expf(-alpha_in[0]));
    }
}

// ---------------------------------------------------------------------------
extern "C" void kernel_launch(void* const* d_in, const int* in_sizes, int n_in,
                              void* d_out, int out_size, void* d_ws, size_t ws_size,
                              hipStream_t stream) {
    const float* x    = (const float*)d_in[0];
    const int*   ei   = (const int*)d_in[1];
    const float* ea   = (const float*)d_in[2];
    const float* W1l  = (const float*)d_in[3];
    const float* b1l  = (const float*)d_in[4];
    const float* W1r  = (const float*)d_in[5];
    const float* b1r  = (const float*)d_in[6];
    const float* We1  = (const float*)d_in[7];
    const float* att1 = (const float*)d_in[8];
    const float* bias1= (const float*)d_in[9];
    const float* W2l  = (const float*)d_in[10];
    const float* b2l  = (const float*)d_in[11];
    const float* W2r  = (const float*)d_in[12];
    const float* b2r  = (const float*)d_in[13];
    const float* We2  = (const float*)d_in[14];
    const float* att2 = (const float*)d_in[15];
    const float* bias2= (const float*)d_in[16];
    const float* alpha= (const float*)d_in[17];
    float* out = (float*)d_out;

    const int F = 128, HC1 = 256, HC2 = 128;
    const int n = in_sizes[0] / F;       // 20000
    const int E = in_sizes[1] / 2;       // 640000
    const int B = (n + 1023) / 1024;     // scan blocks

    char* ws = (char*)d_ws;
    size_t off = 0;
    auto alloc = [&](size_t bytes) { size_t p = off; off += (bytes + 255) & ~(size_t)255; return p; };

    unsigned long long* hist = (unsigned long long*)(ws + alloc((size_t)n * 8 * 8));  // padded x8
    int*   row_ptr = (int*)  (ws + alloc((size_t)(n + 1) * 4));
    int*   wptr    = (int*)  (ws + alloc((size_t)n * 16 * 4));                        // padded x16
    float* ea_loop = (float*)(ws + alloc((size_t)n * 4));
    int*   bsum    = (int*)  (ws + alloc(64 * 4));
    int2*  spk     = (int2*) (ws + alloc((size_t)E * 8));
    unsigned short* xb   = (unsigned short*)(ws + alloc((size_t)n * F * 2));
    unsigned short* Wt1  = (unsigned short*)(ws + alloc((size_t)F * (2 * HC1) * 2));
    unsigned short* Wt2  = (unsigned short*)(ws + alloc((size_t)HC1 * (2 * HC2) * 2));
    float* b1cat   = (float*)(ws + alloc((size_t)2 * HC1 * 4));
    float* b2cat   = (float*)(ws + alloc((size_t)2 * HC2 * 4));
    unsigned short* xlr1 = (unsigned short*)(ws + alloc((size_t)n * 2 * HC1 * 2));
    unsigned short* h1   = (unsigned short*)(ws + alloc((size_t)n * HC1 * 2));
    float* h2      = (float*)(ws + alloc((size_t)n * HC2 * 4));
    float* partial = (float*)(ws + alloc((size_t)256 * 128 * 4));
    unsigned short* xlr2 = xlr1;   // layer-2 projections alias layer-1 buffer
    const int NB_POOL = 256;

    (void)hipMemsetAsync(hist, 0, (size_t)n * 8 * 8, stream);

    int tb = 256;
    edge_hist<<<(E + tb - 1) / tb, tb, 0, stream>>>(ei, ea, hist, E);
    scan_a<<<B, 256, 0, stream>>>(hist, bsum, n);
    scan_b<<<1, 64, 0, stream>>>(bsum, row_ptr, B, n);
    scan_c<<<B, 256, 0, stream>>>(hist, bsum, row_ptr, wptr, ea_loop, n);
    edge_scatter<<<(E + tb - 1) / tb, tb, 0, stream>>>(ei, ea, wptr, spk, E);

    cvt_bf16_v4<<<(n * F / 4 + tb - 1) / tb, tb, 0, stream>>>(x, xb, n * F / 4);
    {
        int total = 2 * F * HC1 + 2 * HC1 * HC2 + 2 * HC1 + 2 * HC2;
        prep_weights<<<(total + tb - 1) / tb, tb, 0, stream>>>(
            W1l, W1r, W2l, W2r, b1l, b1r, b2l, b2r, Wt1, Wt2, b1cat, b2cat, F, HC1, HC2);
    }

    // layer 1: one merged GEMM [n,128]@[128,512] -> xlr1 (xl | xr rows)
    {
        dim3 grid((n + 63) / 64, (2 * HC1) / 64);
        gemm_bf16<<<grid, 256, 0, stream>>>(xb, Wt1, b1cat, xlr1, n, 2 * HC1, F);
    }
    gat_agg<256, 512, 32, true><<<(n + 3) / 4, 256, 0, stream>>>(
        xlr1, We1, att1, bias1, row_ptr, spk, ea_loop, h1, n);

    // layer 2: one merged GEMM [n,256]@[256,256] -> xlr2
    {
        dim3 grid((n + 63) / 64, (2 * HC2) / 64);
        gemm_bf16<<<grid, 256, 0, stream>>>(h1, Wt2, b2cat, xlr2, n, 2 * HC2, HC1);
    }
    gat_agg<128, 256, 128, false><<<(n + 3) / 4, 256, 0, stream>>>(
        xlr2, We2, att2, bias2, row_ptr, spk, ea_loop, h2, n);

    pool_partial<<<NB_POOL, 128, 0, stream>>>(h2, partial, n);
    pool_final<<<1, 1024, 0, stream>>>(partial, NB_POOL, alpha, out, n);
}

// Round 13
// 312.060 us; speedup vs baseline: 1.0315x; 1.0012x over previous
//
#include <hip/hip_runtime.h>
#include <math.h>

#define NEG_SLOPE 0.2f
#define LOG2E 1.4426950408889634f

typedef __attribute__((ext_vector_type(8))) short short8;   // 8 bf16 (4 VGPRs)
typedef __attribute__((ext_vector_type(4))) float f32x4;

__device__ __forceinline__ int imin(int a, int b) { return a < b ? a : b; }

__device__ __forceinline__ unsigned int f2bf(float f) {
    unsigned int u = __float_as_uint(f);
    return (u + 0x7fffu + ((u >> 16) & 1u)) >> 16;   // RNE
}
__device__ __forceinline__ void bf2f(unsigned int u, float& a, float& b) {
    a = __uint_as_float(u << 16);
    b = __uint_as_float(u & 0xffff0000u);
}
// native v_exp_f32 (input already in log2 domain); guarded for compile safety
__device__ __forceinline__ float fast_exp2(float x) {
#if __has_builtin(__builtin_amdgcn_exp2f)
    return __builtin_amdgcn_exp2f(x);
#else
    return exp2f(x);
#endif
}
template <int CTRL>
__device__ __forceinline__ float dpp_add(float v) {
    int t = __builtin_amdgcn_update_dpp(0, __float_as_int(v), CTRL, 0xF, 0xF, true);
    return v + __int_as_float(t);
}

// ---------------------------------------------------------------------------
// Kernel 1: packed histogram. One 64-bit atomic per edge onto a 64B-padded
// slot: low 32 = count, high 32 = ea sum in 2^-16 fixed point.
// ---------------------------------------------------------------------------
__global__ void edge_hist(const int* __restrict__ ei, const float* __restrict__ ea,
                          unsigned long long* __restrict__ hist, int E) {
    int e = blockIdx.x * blockDim.x + threadIdx.x;
    if (e < E) {
        int d = ei[E + e];
        long long fx = (long long)__float2int_rn(ea[e] * 65536.0f);
        unsigned long long v = ((unsigned long long)fx << 32) | 1ull;
        atomicAdd(&hist[(size_t)d * 8], v);
    }
}

// ---------------------------------------------------------------------------
// 3-phase parallel scan over hist (padded stride 8).
// ---------------------------------------------------------------------------
__global__ void scan_a(const unsigned long long* __restrict__ hist, int* __restrict__ bsum, int n) {
    __shared__ int wred[4];
    int base = blockIdx.x * 1024;
    int tid = threadIdx.x;
    int s = 0;
#pragma unroll
    for (int k = 0; k < 4; ++k) {
        int i = base + tid + k * 256;
        if (i < n) s += (int)(hist[(size_t)i * 8] & 0xffffffffull);
    }
#pragma unroll
    for (int off = 32; off > 0; off >>= 1) s += __shfl_xor(s, off, 64);
    if ((tid & 63) == 0) wred[tid >> 6] = s;
    __syncthreads();
    if (tid == 0) bsum[blockIdx.x] = wred[0] + wred[1] + wred[2] + wred[3];
}

__global__ void scan_b(int* __restrict__ bsum, int* __restrict__ row_ptr, int B, int n) {
    int tid = threadIdx.x;           // 64 threads, B <= 64
    int v = (tid < B) ? bsum[tid] : 0;
    int s = v;
#pragma unroll
    for (int off = 1; off < 64; off <<= 1) {
        int t = __shfl_up(s, off, 64);
        if (tid >= off) s += t;
    }
    if (tid < B) bsum[tid] = s - v;  // exclusive
    if (tid == 63) row_ptr[n] = s;   // total
}

__global__ void scan_c(const unsigned long long* __restrict__ hist,
                       const int* __restrict__ bsum, int* __restrict__ row_ptr,
                       int* __restrict__ wptr_pad, float* __restrict__ ea_loop, int n) {
    __shared__ int wtot[4];
    int tid = threadIdx.x;
    int wid = tid >> 6, lane = tid & 63;
    int i0 = blockIdx.x * 1024 + tid * 4;
    int dcnt[4]; float esum[4];
#pragma unroll
    for (int k = 0; k < 4; ++k) {
        if (i0 + k < n) {
            unsigned long long h = hist[(size_t)(i0 + k) * 8];
            dcnt[k] = (int)(h & 0xffffffffull);
            esum[k] = (float)((int)(h >> 32)) * (1.0f / 65536.0f);
        } else { dcnt[k] = 0; esum[k] = 0.0f; }
    }
    int tsum = dcnt[0] + dcnt[1] + dcnt[2] + dcnt[3];
    int s = tsum;
#pragma unroll
    for (int off = 1; off < 64; off <<= 1) {
        int t = __shfl_up(s, off, 64);
        if (lane >= off) s += t;
    }
    if (lane == 63) wtot[wid] = s;
    __syncthreads();
    int wpre = 0;
#pragma unroll
    for (int k = 0; k < 4; ++k) if (k < wid) wpre += wtot[k];
    int pre = bsum[blockIdx.x] + wpre + (s - tsum);
    if (i0 < n) {
        int4 e;
        e.x = pre;
        e.y = pre + dcnt[0];
        e.z = e.y + dcnt[1];
        e.w = e.z + dcnt[2];
        *(int4*)(row_ptr + i0) = e;
        int ev[4] = { e.x, e.y, e.z, e.w };
        float4 el;
        el.x = esum[0] / fmaxf((float)dcnt[0], 1.0f);
        el.y = esum[1] / fmaxf((float)dcnt[1], 1.0f);
        el.z = esum[2] / fmaxf((float)dcnt[2], 1.0f);
        el.w = esum[3] / fmaxf((float)dcnt[3], 1.0f);
        *(float4*)(ea_loop + i0) = el;
#pragma unroll
        for (int k = 0; k < 4; ++k) wptr_pad[(size_t)(i0 + k) * 16] = ev[k];
    }
}

// ---------------------------------------------------------------------------
// Kernel 3: scatter edges into CSR order; (src,w) packed as int2.
// ---------------------------------------------------------------------------
__global__ void edge_scatter(const int* __restrict__ ei, const float* __restrict__ ea,
                             int* __restrict__ wptr_pad, int2* __restrict__ spk, int E) {
    int e = blockIdx.x * blockDim.x + threadIdx.x;
    if (e < E) {
        int d = ei[E + e];
        int pos = atomicAdd(&wptr_pad[(size_t)d * 16], 1);
        spk[pos] = make_int2(ei[e], __float_as_int(ea[e]));
    }
}

// ---------------------------------------------------------------------------
// Conversion: x -> bf16 vec4
// ---------------------------------------------------------------------------
__global__ void cvt_bf16_v4(const float* __restrict__ in, unsigned short* __restrict__ out, int sz4) {
    int i = blockIdx.x * blockDim.x + threadIdx.x;
    if (i < sz4) {
        float4 v = ((const float4*)in)[i];
        uint2 r;
        r.x = f2bf(v.x) | (f2bf(v.y) << 16);
        r.y = f2bf(v.z) | (f2bf(v.w) << 16);
        ((uint2*)out)[i] = r;
    }
}

// ---------------------------------------------------------------------------
// Fused weight prep: 4 transposed bf16 conversions + 2 bias concats.
// ---------------------------------------------------------------------------
__global__ void prep_weights(const float* __restrict__ W1l, const float* __restrict__ W1r,
                             const float* __restrict__ W2l, const float* __restrict__ W2r,
                             const float* __restrict__ b1l, const float* __restrict__ b1r,
                             const float* __restrict__ b2l, const float* __restrict__ b2r,
                             unsigned short* __restrict__ Wt1, unsigned short* __restrict__ Wt2,
                             float* __restrict__ b1cat, float* __restrict__ b2cat,
                             int F, int HC1, int HC2) {
    int S1 = F * HC1, S2 = HC1 * HC2;
    int i = blockIdx.x * blockDim.x + threadIdx.x;
    if (i < S1) {
        int k = i / HC1, nn = i - k * HC1;
        Wt1[(size_t)nn * F + k] = (unsigned short)f2bf(W1l[i]);
    } else if (i < 2 * S1) {
        int j = i - S1;
        int k = j / HC1, nn = j - k * HC1;
        Wt1[(size_t)(HC1 + nn) * F + k] = (unsigned short)f2bf(W1r[j]);
    } else if (i < 2 * S1 + S2) {
        int j = i - 2 * S1;
        int k = j / HC2, nn = j - k * HC2;
        Wt2[(size_t)nn * HC1 + k] = (unsigned short)f2bf(W2l[j]);
    } else if (i < 2 * S1 + 2 * S2) {
        int j = i - 2 * S1 - S2;
        int k = j / HC2, nn = j - k * HC2;
        Wt2[(size_t)(HC2 + nn) * HC1 + k] = (unsigned short)f2bf(W2r[j]);
    } else if (i < 2 * S1 + 2 * S2 + 2 * HC1) {
        int j = i - 2 * S1 - 2 * S2;
        b1cat[j] = (j < HC1) ? b1l[j] : b1r[j - HC1];
    } else if (i < 2 * S1 + 2 * S2 + 2 * HC1 + 2 * HC2) {
        int j = i - 2 * S1 - 2 * S2 - 2 * HC1;
        b2cat[j] = (j < HC2) ? b2l[j] : b2r[j - HC2];
    }
}

// ---------------------------------------------------------------------------
// Kernel 4: bf16 MFMA GEMM + bias (B pre-transposed), 64x64 tile, BK=32.
// ---------------------------------------------------------------------------
__global__ void __launch_bounds__(256)
gemm_bf16(const unsigned short* __restrict__ A, const unsigned short* __restrict__ Bt,
          const float* __restrict__ bias, unsigned short* __restrict__ C,
          int M, int N, int K) {
    __shared__ __attribute__((aligned(16))) unsigned short As[64 * 40];
    __shared__ __attribute__((aligned(16))) unsigned short Bs[64 * 40];
    int tid  = threadIdx.x;
    int wave = tid >> 6, lane = tid & 63;
    int m0 = blockIdx.x * 64, n0 = blockIdx.y * 64;
    int row = tid >> 2, kg = (tid & 3) * 8;

    f32x4 acc[4] = {};
    for (int kk = 0; kk < K; kk += 32) {
        int gm = m0 + row;
        uint4 av;
        if (gm < M) av = *(const uint4*)(A + (size_t)gm * K + kk + kg);
        else        av = make_uint4(0, 0, 0, 0);
        *(uint4*)&As[row * 40 + kg] = av;
        uint4 bv = *(const uint4*)(Bt + (size_t)(n0 + row) * K + kk + kg);
        *(uint4*)&Bs[row * 40 + kg] = bv;
        __syncthreads();
        short8 a = *(const short8*)&As[(wave * 16 + (lane & 15)) * 40 + (lane >> 4) * 8];
#pragma unroll
        for (int g = 0; g < 4; ++g) {
            short8 b = *(const short8*)&Bs[(g * 16 + (lane & 15)) * 40 + (lane >> 4) * 8];
            acc[g] = __builtin_amdgcn_mfma_f32_16x16x32_bf16(a, b, acc[g], 0, 0, 0);
        }
        __syncthreads();
    }
#pragma unroll
    for (int g = 0; g < 4; ++g) {
        int col = n0 + g * 16 + (lane & 15);
        float bs = bias[col];
#pragma unroll
        for (int r = 0; r < 4; ++r) {
            int grow = m0 + wave * 16 + (lane >> 4) * 4 + r;
            if (grow < M) C[(size_t)grow * N + col] = (unsigned short)f2bf(acc[g][r] + bs);
        }
    }
}

// ---------------------------------------------------------------------------
// helpers for gat_agg
// ---------------------------------------------------------------------------
template <int NV>
__device__ __forceinline__ void ld_row(float* r, const float* p) {
    if constexpr (NV == 4) {
        float4 t = *(const float4*)p;
        r[0] = t.x; r[1] = t.y; r[2] = t.z; r[3] = t.w;
    } else {
        float2 t = *(const float2*)p;
        r[0] = t.x; r[1] = t.y;
    }
}
template <int NV>
__device__ __forceinline__ uint2 ld_bf(const unsigned short* __restrict__ base, int laneoff) {
    uint2 r;
    if constexpr (NV == 4) r = *(const uint2*)(base + laneoff);
    else { r.x = *(const unsigned int*)(base + laneoff); r.y = 0; }
    return r;
}
template <int G>
__device__ __forceinline__ float grp_reduce(float vs) {
    vs = dpp_add<0xB1>(vs);              // xor 1
    vs = dpp_add<0x4E>(vs);              // xor 2
    vs = dpp_add<0x141>(vs);             // xor 4 (row_half_mirror)
    if constexpr (G >= 16) vs = dpp_add<0x140>(vs);   // xor 8 (row_mirror)
    if constexpr (G >= 32) {             // xor 16
        int t = __builtin_amdgcn_ds_swizzle(__float_as_int(vs), 0x401F);
        vs += __int_as_float(t);
    }
    if constexpr (G >= 64) vs += __shfl_xor(vs, 32, 64);
    return vs;
}

// ---------------------------------------------------------------------------
// Kernel 5: fused GATv2 gather(bf16) + score + softmax + aggregate + relu.
// Unroll-4 edge pipeline.  __launch_bounds__(256,4) gives the register
// allocator ~128 VGPR headroom so the 4-slot prefetch stays live (at the
// default heuristic the kernel was squeezed to 32 VGPR — below the ~44 the
// written pipeline needs — and the compiler serialized the loads).
// att coefficients pre-scaled by log2e; pr = native v_exp_f32.
// ---------------------------------------------------------------------------
template <int HC, int STRIDE, int C, bool OUT_BF16>
__global__ void __launch_bounds__(256, 4)
gat_agg(const unsigned short* __restrict__ xlr,
        const float* __restrict__ We, const float* __restrict__ att,
        const float* __restrict__ bias,
        const int* __restrict__ row_ptr, const int2* __restrict__ spk,
        const float* __restrict__ ea_loop,
        void* __restrict__ out, int n) {
    constexpr int NV = HC / 64;      // channels per lane
    constexpr int G  = C / NV;       // lanes per head
    int wave = threadIdx.x >> 6;
    int lane = threadIdx.x & 63;
    int node = blockIdx.x * 4 + wave;
    if (node >= n) return;
    int laneoff = lane * NV;

    float xr_r[NV], We_r[NV], att6[NV], att4[NV], o[NV];
    {
        uint2 u = ld_bf<NV>(xlr + (size_t)node * STRIDE + HC, laneoff);
        bf2f(u.x, xr_r[0], xr_r[1]);
        if constexpr (NV == 4) bf2f(u.y, xr_r[2], xr_r[3]);
    }
    ld_row<NV>(We_r, We + laneoff);
    {
        float att_r[NV];
        ld_row<NV>(att_r, att + laneoff);
#pragma unroll
        for (int j = 0; j < NV; ++j) {
            att6[j] = 0.6f * LOG2E * att_r[j];
            att4[j] = 0.4f * LOG2E * att_r[j];
        }
    }
#pragma unroll
    for (int j = 0; j < NV; ++j) o[j] = 0.0f;

    int start = __builtin_amdgcn_readfirstlane(row_ptr[node]);
    int end   = __builtin_amdgcn_readfirstlane(row_ptr[node + 1]);
    float ea_l = ea_loop[node];
    float l = 0.0f;

    auto process = [&](uint2 xu, float w) {
        float xf[NV];
        bf2f(xu.x, xf[0], xf[1]);
        if constexpr (NV == 4) bf2f(xu.y, xf[2], xf[3]);
        float vs = 0.0f;
#pragma unroll
        for (int j = 0; j < NV; ++j) {
            float mm = xf[j] + fmaf(w, We_r[j], xr_r[j]);
            vs = fmaf(att6[j], mm, vs);
            vs = fmaf(att4[j], fabsf(mm), vs);
        }
        vs = grp_reduce<G>(vs);
        float pr = fast_exp2(vs);
        l += pr;
#pragma unroll
        for (int j = 0; j < NV; ++j) o[j] = fmaf(pr, xf[j], o[j]);
    };

    // ---- self-loop edge ----
    process(ld_bf<NV>(xlr + (size_t)node * STRIDE, laneoff), ea_l);

    // ---- real edges, batches of 64, unroll-4 with 4 slots in flight ----
    int cnt = end - start;
    for (int b0 = 0; b0 < cnt; b0 += 64) {
        int rem = imin(64, cnt - b0);
        int idx = start + b0 + lane;
        int idxc = imin(idx, end - 1);
        int2 pv = spk[idxc];

        auto rl = [&](int j) {
            int s = __builtin_amdgcn_readlane(pv.x, j);
            return ld_bf<NV>(xlr + (size_t)s * STRIDE, laneoff);
        };
        auto rw = [&](int j) {
            return __int_as_float(__builtin_amdgcn_readlane(pv.y, j));
        };

        int rc = rem - 1;
        uint2 X0 = rl(0),            X1 = rl(imin(1, rc)),
              X2 = rl(imin(2, rc)),  X3 = rl(imin(3, rc));
        float W0 = rw(0),            W1 = rw(imin(1, rc)),
              W2 = rw(imin(2, rc)),  W3 = rw(imin(3, rc));

        int j = 0;
        for (; j + 4 <= rem; j += 4) {
            uint2 Y0 = rl(imin(j + 4, rc)), Y1 = rl(imin(j + 5, rc)),
                  Y2 = rl(imin(j + 6, rc)), Y3 = rl(imin(j + 7, rc));
            float U0 = rw(imin(j + 4, rc)), U1 = rw(imin(j + 5, rc)),
                  U2 = rw(imin(j + 6, rc)), U3 = rw(imin(j + 7, rc));
            process(X0, W0); process(X1, W1); process(X2, W2); process(X3, W3);
            X0 = Y0; X1 = Y1; X2 = Y2; X3 = Y3;
            W0 = U0; W1 = U1; W2 = U2; W3 = U3;
        }
        if (j < rem) {
            process(X0, W0);
            if (j + 1 < rem) {
                process(X1, W1);
                if (j + 2 < rem) process(X2, W2);
            }
        }
    }

    float inv = 1.0f / (l + 1e-16f);
    float b_r[NV];
    ld_row<NV>(b_r, bias + laneoff);
    float v[NV];
#pragma unroll
    for (int j = 0; j < NV; ++j) v[j] = fmaxf(o[j] * inv + b_r[j], 0.0f);

    if constexpr (OUT_BF16) {
        unsigned short* op = (unsigned short*)out + (size_t)node * HC + laneoff;
        if constexpr (NV == 4) {
            uint2 t;
            t.x = f2bf(v[0]) | (f2bf(v[1]) << 16);
            t.y = f2bf(v[2]) | (f2bf(v[3]) << 16);
            *(uint2*)op = t;
        } else {
            *(unsigned int*)op = f2bf(v[0]) | (f2bf(v[1]) << 16);
        }
    } else {
        float* op = (float*)out + (size_t)node * HC + laneoff;
        if constexpr (NV == 4) { *(float4*)op = make_float4(v[0], v[1], v[2], v[3]); }
        else                   { *(float2*)op = make_float2(v[0], v[1]); }
    }
}

// ---------------------------------------------------------------------------
// Kernel 6: column partial sums of h2 [n,128] -> partial[gridDim.x*128]
// ---------------------------------------------------------------------------
__global__ void pool_partial(const float* __restrict__ h2, float* __restrict__ partial, int n) {
    int t = threadIdx.x;
    float s = 0.0f;
    for (int r = blockIdx.x; r < n; r += gridDim.x) s += h2[(size_t)r * 128 + t];
    partial[blockIdx.x * 128 + t] = s;
}

// ---------------------------------------------------------------------------
// Kernel 7: finish pooling, softmax over 128, sigmoid(alpha). 1024 threads.
// ---------------------------------------------------------------------------
__global__ void __launch_bounds__(1024)
pool_final(const float* __restrict__ partial, int nb,
           const float* __restrict__ alpha_in,
           float* __restrict__ out, int n) {
    __shared__ float acc[8][128];
    __shared__ float red[4];
    int t = threadIdx.x & 127;        // column
    int g = threadIdx.x >> 7;         // group 0..7
    float s = 0.0f;
    for (int b = g; b < nb; b += 8) s += partial[b * 128 + t];
    acc[g][t] = s;
    __syncthreads();
    if (threadIdx.x < 128) {
        float tot = 0.0f;
#pragma unroll
        for (int k = 0; k < 8; ++k) tot += acc[k][t];
        float mean = tot / (float)n;
        float mx = mean;
#pragma unroll
        for (int off = 32; off > 0; off >>= 1) mx = fmaxf(mx, __shfl_xor(mx, off, 64));
        if ((t & 63) == 0) red[t >> 6] = mx;
        __syncthreads();
        mx = fmaxf(red[0], red[1]);
        float ex = __expf(mean - mx);
        float sm = ex;
#pragma unroll
        for (int off = 32; off > 0; off >>= 1) sm += __shfl_xor(sm, off, 64);
        if ((t & 63) == 0) red[2 + (t >> 6)] = sm;
        __syncthreads();
        sm = red[2] + red[3];
        out[t] = ex / sm;
        if (t == 0) out[128] = 1.0f / (1.0f + __expf(-alpha_in[0]));
    }
}

// ---------------------------------------------------------------------------
extern "C" void kernel_launch(void* const* d_in, const int* in_sizes, int n_in,
                              void* d_out, int out_size, void* d_ws, size_t ws_size,
                              hipStream_t stream) {
    const float* x    = (const float*)d_in[0];
    const int*   ei   = (const int*)d_in[1];
    const float* ea   = (const float*)d_in[2];
    const float* W1l  = (const float*)d_in[3];
    const float* b1l  = (const float*)d_in[4];
    const float* W1r  = (const float*)d_in[5];
    const float* b1r  = (const float*)d_in[6];
    const float* We1  = (const float*)d_in[7];
    const float* att1 = (const float*)d_in[8];
    const float* bias1= (const float*)d_in[9];
    const float* W2l  = (const float*)d_in[10];
    const float* b2l  = (const float*)d_in[11];
    const float* W2r  = (const float*)d_in[12];
    const float* b2r  = (const float*)d_in[13];
    const float* We2  = (const float*)d_in[14];
    const float* att2 = (const float*)d_in[15];
    const float* bias2= (const float*)d_in[16];
    const float* alpha= (const float*)d_in[17];
    float* out = (float*)d_out;

    const int F = 128, HC1 = 256, HC2 = 128;
    const int n = in_sizes[0] / F;       // 20000
    const int E = in_sizes[1] / 2;       // 640000
    const int B = (n + 1023) / 1024;     // scan blocks

    char* ws = (char*)d_ws;
    size_t off = 0;
    auto alloc = [&](size_t bytes) { size_t p = off; off += (bytes + 255) & ~(size_t)255; return p; };

    unsigned long long* hist = (unsigned long long*)(ws + alloc((size_t)n * 8 * 8));  // padded x8
    int*   row_ptr = (int*)  (ws + alloc((size_t)(n + 1) * 4));
    int*   wptr    = (int*)  (ws + alloc((size_t)n * 16 * 4));                        // padded x16
    float* ea_loop = (float*)(ws + alloc((size_t)n * 4));
    int*   bsum    = (int*)  (ws + alloc(64 * 4));
    int2*  spk     = (int2*) (ws + alloc((size_t)E * 8));
    unsigned short* xb   = (unsigned short*)(ws + alloc((size_t)n * F * 2));
    unsigned short* Wt1  = (unsigned short*)(ws + alloc((size_t)F * (2 * HC1) * 2));
    unsigned short* Wt2  = (unsigned short*)(ws + alloc((size_t)HC1 * (2 * HC2) * 2));
    float* b1cat   = (float*)(ws + alloc((size_t)2 * HC1 * 4));
    float* b2cat   = (float*)(ws + alloc((size_t)2 * HC2 * 4));
    unsigned short* xlr1 = (unsigned short*)(ws + alloc((size_t)n * 2 * HC1 * 2));
    unsigned short* h1   = (unsigned short*)(ws + alloc((size_t)n * HC1 * 2));
    float* h2      = (float*)(ws + alloc((size_t)n * HC2 * 4));
    float* partial = (float*)(ws + alloc((size_t)256 * 128 * 4));
    unsigned short* xlr2 = xlr1;   // layer-2 projections alias layer-1 buffer
    const int NB_POOL = 256;

    (void)hipMemsetAsync(hist, 0, (size_t)n * 8 * 8, stream);

    int tb = 256;
    edge_hist<<<(E + tb - 1) / tb, tb, 0, stream>>>(ei, ea, hist, E);
    scan_a<<<B, 256, 0, stream>>>(hist, bsum, n);
    scan_b<<<1, 64, 0, stream>>>(bsum, row_ptr, B, n);
    scan_c<<<B, 256, 0, stream>>>(hist, bsum, row_ptr, wptr, ea_loop, n);
    edge_scatter<<<(E + tb - 1) / tb, tb, 0, stream>>>(ei, ea, wptr, spk, E);

    cvt_bf16_v4<<<(n * F / 4 + tb - 1) / tb, tb, 0, stream>>>(x, xb, n * F / 4);
    {
        int total = 2 * F * HC1 + 2 * HC1 * HC2 + 2 * HC1 + 2 * HC2;
        prep_weights<<<(total + tb - 1) / tb, tb, 0, stream>>>(
            W1l, W1r, W2l, W2r, b1l, b1r, b2l, b2r, Wt1, Wt2, b1cat, b2cat, F, HC1, HC2);
    }

    // layer 1: one merged GEMM [n,128]@[128,512] -> xlr1 (xl | xr rows)
    {
        dim3 grid((n + 63) / 64, (2 * HC1) / 64);
        gemm_bf16<<<grid, 256, 0, stream>>>(xb, Wt1, b1cat, xlr1, n, 2 * HC1, F);
    }
    gat_agg<256, 512, 32, true><<<(n + 3) / 4, 256, 0, stream>>>(
        xlr1, We1, att1, bias1, row_ptr, spk, ea_loop, h1, n);

    // layer 2: one merged GEMM [n,256]@[256,256] -> xlr2
    {
        dim3 grid((n + 63) / 64, (2 * HC2) / 64);
        gemm_bf16<<<grid, 256, 0, stream>>>(h1, Wt2, b2cat, xlr2, n, 2 * HC2, HC1);
    }
    gat_agg<128, 256, 128, false><<<(n + 3) / 4, 256, 0, stream>>>(
        xlr2, We2, att2, bias2, row_ptr, spk, ea_loop, h2, n);

    pool_partial<<<NB_POOL, 128, 0, stream>>>(h2, partial, n);
    pool_final<<<1, 1024, 0, stream>>>(partial, NB_POOL, alpha, out, n);
}

// Round 14
// 279.614 us; speedup vs baseline: 1.1512x; 1.1160x over previous
//
#include <hip/hip_runtime.h>
#include <math.h>

#define NEG_SLOPE 0.2f
#define LOG2E 1.4426950408889634f

typedef __attribute__((ext_vector_type(8))) short short8;   // 8 bf16 (4 VGPRs)
typedef __attribute__((ext_vector_type(4))) float f32x4;
typedef __attribute__((ext_vector_type(2))) float v2f;

__device__ __forceinline__ int imin(int a, int b) { return a < b ? a : b; }

__device__ __forceinline__ unsigned int f2bf(float f) {
    unsigned int u = __float_as_uint(f);
    return (u + 0x7fffu + ((u >> 16) & 1u)) >> 16;   // RNE
}
__device__ __forceinline__ void bf2f(unsigned int u, float& a, float& b) {
    a = __uint_as_float(u << 16);
    b = __uint_as_float(u & 0xffff0000u);
}
__device__ __forceinline__ float fast_exp2(float x) {
#if __has_builtin(__builtin_amdgcn_exp2f)
    return __builtin_amdgcn_exp2f(x);
#else
    return exp2f(x);
#endif
}
// fp8 (OCP e4m3 on gfx950) hardware pack/unpack
__device__ __forceinline__ unsigned char f2fp8(float v) {
    return (unsigned char)(__builtin_amdgcn_cvt_pk_fp8_f32(v, v, 0, false) & 0xff);
}
template <int CTRL>
__device__ __forceinline__ float dpp_add(float v) {
    int t = __builtin_amdgcn_update_dpp(0, __float_as_int(v), CTRL, 0xF, 0xF, true);
    return v + __int_as_float(t);
}

// ---------------------------------------------------------------------------
// Fused prep kernel: three disjoint index ranges in one launch.
//  [0, E)            : packed histogram (64-bit atomic, 64B-padded slots)
//  [E, E+nF4)        : x fp32 -> bf16 (vec4)
//  [E+nF4, ..+WTOT)  : weight transposes -> bf16 + bias concats
// ---------------------------------------------------------------------------
__global__ void fused_prep(const int* __restrict__ ei, const float* __restrict__ ea,
                           unsigned long long* __restrict__ hist, int E,
                           const float* __restrict__ x, unsigned short* __restrict__ xb, int nF4,
                           const float* __restrict__ W1l, const float* __restrict__ W1r,
                           const float* __restrict__ W2l, const float* __restrict__ W2r,
                           const float* __restrict__ b1l, const float* __restrict__ b1r,
                           const float* __restrict__ b2l, const float* __restrict__ b2r,
                           unsigned short* __restrict__ Wt1, unsigned short* __restrict__ Wt2,
                           float* __restrict__ b1cat, float* __restrict__ b2cat,
                           int F, int HC1, int HC2) {
    int i = blockIdx.x * blockDim.x + threadIdx.x;
    if (i < E) {
        int d = ei[E + i];
        long long fx = (long long)__float2int_rn(ea[i] * 65536.0f);
        unsigned long long v = ((unsigned long long)fx << 32) | 1ull;
        atomicAdd(&hist[(size_t)d * 8], v);
        return;
    }
    int j = i - E;
    if (j < nF4) {
        float4 v = ((const float4*)x)[j];
        uint2 r;
        r.x = f2bf(v.x) | (f2bf(v.y) << 16);
        r.y = f2bf(v.z) | (f2bf(v.w) << 16);
        ((uint2*)xb)[j] = r;
        return;
    }
    int k = j - nF4;
    int S1 = F * HC1, S2 = HC1 * HC2;
    if (k < S1) {
        int kk = k / HC1, nn = k - kk * HC1;
        Wt1[(size_t)nn * F + kk] = (unsigned short)f2bf(W1l[k]);
    } else if (k < 2 * S1) {
        int m = k - S1;
        int kk = m / HC1, nn = m - kk * HC1;
        Wt1[(size_t)(HC1 + nn) * F + kk] = (unsigned short)f2bf(W1r[m]);
    } else if (k < 2 * S1 + S2) {
        int m = k - 2 * S1;
        int kk = m / HC2, nn = m - kk * HC2;
        Wt2[(size_t)nn * HC1 + kk] = (unsigned short)f2bf(W2l[m]);
    } else if (k < 2 * S1 + 2 * S2) {
        int m = k - 2 * S1 - S2;
        int kk = m / HC2, nn = m - kk * HC2;
        Wt2[(size_t)(HC2 + nn) * HC1 + kk] = (unsigned short)f2bf(W2r[m]);
    } else if (k < 2 * S1 + 2 * S2 + 2 * HC1) {
        int m = k - 2 * S1 - 2 * S2;
        b1cat[m] = (m < HC1) ? b1l[m] : b1r[m - HC1];
    } else if (k < 2 * S1 + 2 * S2 + 2 * HC1 + 2 * HC2) {
        int m = k - 2 * S1 - 2 * S2 - 2 * HC1;
        b2cat[m] = (m < HC2) ? b2l[m] : b2r[m - HC2];
    }
}

// ---------------------------------------------------------------------------
// 3-phase parallel scan over hist (padded stride 8).
// ---------------------------------------------------------------------------
__global__ void scan_a(const unsigned long long* __restrict__ hist, int* __restrict__ bsum, int n) {
    __shared__ int wred[4];
    int base = blockIdx.x * 1024;
    int tid = threadIdx.x;
    int s = 0;
#pragma unroll
    for (int k = 0; k < 4; ++k) {
        int i = base + tid + k * 256;
        if (i < n) s += (int)(hist[(size_t)i * 8] & 0xffffffffull);
    }
#pragma unroll
    for (int off = 32; off > 0; off >>= 1) s += __shfl_xor(s, off, 64);
    if ((tid & 63) == 0) wred[tid >> 6] = s;
    __syncthreads();
    if (tid == 0) bsum[blockIdx.x] = wred[0] + wred[1] + wred[2] + wred[3];
}

__global__ void scan_b(int* __restrict__ bsum, int* __restrict__ row_ptr, int B, int n) {
    int tid = threadIdx.x;           // 64 threads, B <= 64
    int v = (tid < B) ? bsum[tid] : 0;
    int s = v;
#pragma unroll
    for (int off = 1; off < 64; off <<= 1) {
        int t = __shfl_up(s, off, 64);
        if (tid >= off) s += t;
    }
    if (tid < B) bsum[tid] = s - v;  // exclusive
    if (tid == 63) row_ptr[n] = s;   // total
}

__global__ void scan_c(const unsigned long long* __restrict__ hist,
                       const int* __restrict__ bsum, int* __restrict__ row_ptr,
                       int* __restrict__ wptr_pad, float* __restrict__ ea_loop, int n) {
    __shared__ int wtot[4];
    int tid = threadIdx.x;
    int wid = tid >> 6, lane = tid & 63;
    int i0 = blockIdx.x * 1024 + tid * 4;
    int dcnt[4]; float esum[4];
#pragma unroll
    for (int k = 0; k < 4; ++k) {
        if (i0 + k < n) {
            unsigned long long h = hist[(size_t)(i0 + k) * 8];
            dcnt[k] = (int)(h & 0xffffffffull);
            esum[k] = (float)((int)(h >> 32)) * (1.0f / 65536.0f);
        } else { dcnt[k] = 0; esum[k] = 0.0f; }
    }
    int tsum = dcnt[0] + dcnt[1] + dcnt[2] + dcnt[3];
    int s = tsum;
#pragma unroll
    for (int off = 1; off < 64; off <<= 1) {
        int t = __shfl_up(s, off, 64);
        if (lane >= off) s += t;
    }
    if (lane == 63) wtot[wid] = s;
    __syncthreads();
    int wpre = 0;
#pragma unroll
    for (int k = 0; k < 4; ++k) if (k < wid) wpre += wtot[k];
    int pre = bsum[blockIdx.x] + wpre + (s - tsum);
    if (i0 < n) {
        int4 e;
        e.x = pre;
        e.y = pre + dcnt[0];
        e.z = e.y + dcnt[1];
        e.w = e.z + dcnt[2];
        *(int4*)(row_ptr + i0) = e;
        int ev[4] = { e.x, e.y, e.z, e.w };
        float4 el;
        el.x = esum[0] / fmaxf((float)dcnt[0], 1.0f);
        el.y = esum[1] / fmaxf((float)dcnt[1], 1.0f);
        el.z = esum[2] / fmaxf((float)dcnt[2], 1.0f);
        el.w = esum[3] / fmaxf((float)dcnt[3], 1.0f);
        *(float4*)(ea_loop + i0) = el;
#pragma unroll
        for (int k = 0; k < 4; ++k) wptr_pad[(size_t)(i0 + k) * 16] = ev[k];
    }
}

// ---------------------------------------------------------------------------
// scatter edges into CSR order; (src,w) packed as int2.
// ---------------------------------------------------------------------------
__global__ void edge_scatter(const int* __restrict__ ei, const float* __restrict__ ea,
                             int* __restrict__ wptr_pad, int2* __restrict__ spk, int E) {
    int e = blockIdx.x * blockDim.x + threadIdx.x;
    if (e < E) {
        int d = ei[E + e];
        int pos = atomicAdd(&wptr_pad[(size_t)d * 16], 1);
        spk[pos] = make_int2(ei[e], __float_as_int(ea[e]));
    }
}

// ---------------------------------------------------------------------------
// bf16 MFMA GEMM + bias (B pre-transposed), 64x64 tile, BK=32.
// OUT_FP8: epilogue packs to fp8 (e4m3, hardware RNE) else bf16.
// ---------------------------------------------------------------------------
template <bool OUT_FP8>
__global__ void __launch_bounds__(256)
gemm_bf16(const unsigned short* __restrict__ A, const unsigned short* __restrict__ Bt,
          const float* __restrict__ bias, void* __restrict__ Cv,
          int M, int N, int K) {
    __shared__ __attribute__((aligned(16))) unsigned short As[64 * 40];
    __shared__ __attribute__((aligned(16))) unsigned short Bs[64 * 40];
    int tid  = threadIdx.x;
    int wave = tid >> 6, lane = tid & 63;
    int m0 = blockIdx.x * 64, n0 = blockIdx.y * 64;
    int row = tid >> 2, kg = (tid & 3) * 8;

    f32x4 acc[4] = {};
    for (int kk = 0; kk < K; kk += 32) {
        int gm = m0 + row;
        uint4 av;
        if (gm < M) av = *(const uint4*)(A + (size_t)gm * K + kk + kg);
        else        av = make_uint4(0, 0, 0, 0);
        *(uint4*)&As[row * 40 + kg] = av;
        uint4 bv = *(const uint4*)(Bt + (size_t)(n0 + row) * K + kk + kg);
        *(uint4*)&Bs[row * 40 + kg] = bv;
        __syncthreads();
        short8 a = *(const short8*)&As[(wave * 16 + (lane & 15)) * 40 + (lane >> 4) * 8];
#pragma unroll
        for (int g = 0; g < 4; ++g) {
            short8 b = *(const short8*)&Bs[(g * 16 + (lane & 15)) * 40 + (lane >> 4) * 8];
            acc[g] = __builtin_amdgcn_mfma_f32_16x16x32_bf16(a, b, acc[g], 0, 0, 0);
        }
        __syncthreads();
    }
#pragma unroll
    for (int g = 0; g < 4; ++g) {
        int col = n0 + g * 16 + (lane & 15);
        float bs = bias[col];
#pragma unroll
        for (int r = 0; r < 4; ++r) {
            int grow = m0 + wave * 16 + (lane >> 4) * 4 + r;
            if (grow < M) {
                float val = acc[g][r] + bs;
                if constexpr (OUT_FP8) {
                    ((unsigned char*)Cv)[(size_t)grow * N + col] = f2fp8(val);
                } else {
                    ((unsigned short*)Cv)[(size_t)grow * N + col] = (unsigned short)f2bf(val);
                }
            }
        }
    }
}

// ---------------------------------------------------------------------------
// helpers for gat_agg (fp8 gather path)
// ---------------------------------------------------------------------------
template <int NV>
__device__ __forceinline__ void ld_row(float* r, const float* p) {
    if constexpr (NV == 4) {
        float4 t = *(const float4*)p;
        r[0] = t.x; r[1] = t.y; r[2] = t.z; r[3] = t.w;
    } else {
        float2 t = *(const float2*)p;
        r[0] = t.x; r[1] = t.y;
    }
}
template <int NV>
__device__ __forceinline__ unsigned int ld_fp8(const unsigned char* __restrict__ base, int off) {
    if constexpr (NV == 4) return *(const unsigned int*)(base + off);
    else                   return (unsigned int)(*(const unsigned short*)(base + off));
}
template <int NV>
__device__ __forceinline__ void unp_fp8(unsigned int u, float* xf) {
    v2f p0 = __builtin_amdgcn_cvt_pk_f32_fp8(u, false);
    xf[0] = p0.x; xf[1] = p0.y;
    if constexpr (NV == 4) {
        v2f p1 = __builtin_amdgcn_cvt_pk_f32_fp8(u, true);
        xf[2] = p1.x; xf[3] = p1.y;
    }
}
template <int G>
__device__ __forceinline__ float grp_reduce(float vs) {
    vs = dpp_add<0xB1>(vs);              // xor 1
    vs = dpp_add<0x4E>(vs);              // xor 2
    vs = dpp_add<0x141>(vs);             // xor 4 (row_half_mirror)
    if constexpr (G >= 16) vs = dpp_add<0x140>(vs);   // xor 8 (row_mirror)
    if constexpr (G >= 32) {             // xor 16
        int t = __builtin_amdgcn_ds_swizzle(__float_as_int(vs), 0x401F);
        vs += __int_as_float(t);
    }
    if constexpr (G >= 64) vs += __shfl_xor(vs, 32, 64);
    return vs;
}

// ---------------------------------------------------------------------------
// fused GATv2 gather(fp8) + score + softmax + aggregate + relu.
// xlr rows are fp8 bytes: xl at [0,HC), xr at [HC,2HC), row stride = STRIDE B.
// Unroll-4 edge pipeline; gather slot is 1 VGPR (L1) so pipeline state fits
// the allocator's 32-VGPR budget.  att coeffs pre-scaled by log2e.
// OUT_MODE 0: dense bf16 rows.  OUT_MODE 1: fused pooling — relu'd row
// atomicAdded into partial[blockIdx&255][128] (skips h2 entirely).
// ---------------------------------------------------------------------------
template <int HC, int STRIDE, int C, int OUT_MODE>
__global__ void __launch_bounds__(256)
gat_agg(const unsigned char* __restrict__ xlr,
        const float* __restrict__ We, const float* __restrict__ att,
        const float* __restrict__ bias,
        const int* __restrict__ row_ptr, const int2* __restrict__ spk,
        const float* __restrict__ ea_loop,
        void* __restrict__ out, int n) {
    constexpr int NV = HC / 64;      // channels per lane
    constexpr int G  = C / NV;       // lanes per head
    int wave = threadIdx.x >> 6;
    int lane = threadIdx.x & 63;
    int node = blockIdx.x * 4 + wave;
    if (node >= n) return;
    int laneoff = lane * NV;         // byte offset (1B/channel)

    float xr_r[NV], We_r[NV], att6[NV], att4[NV], o[NV];
    unp_fp8<NV>(ld_fp8<NV>(xlr + (size_t)node * STRIDE + HC, laneoff), xr_r);
    ld_row<NV>(We_r, We + laneoff);
    {
        float att_r[NV];
        ld_row<NV>(att_r, att + laneoff);
#pragma unroll
        for (int j = 0; j < NV; ++j) {
            att6[j] = 0.6f * LOG2E * att_r[j];
            att4[j] = 0.4f * LOG2E * att_r[j];
        }
    }
#pragma unroll
    for (int j = 0; j < NV; ++j) o[j] = 0.0f;

    int start = __builtin_amdgcn_readfirstlane(row_ptr[node]);
    int end   = __builtin_amdgcn_readfirstlane(row_ptr[node + 1]);
    float ea_l = ea_loop[node];
    float l = 0.0f;

    auto process = [&](unsigned int xu, float w) {
        float xf[NV];
        unp_fp8<NV>(xu, xf);
        float vs = 0.0f;
#pragma unroll
        for (int j = 0; j < NV; ++j) {
            float mm = xf[j] + fmaf(w, We_r[j], xr_r[j]);
            vs = fmaf(att6[j], mm, vs);
            vs = fmaf(att4[j], fabsf(mm), vs);
        }
        vs = grp_reduce<G>(vs);
        float pr = fast_exp2(vs);
        l += pr;
#pragma unroll
        for (int j = 0; j < NV; ++j) o[j] = fmaf(pr, xf[j], o[j]);
    };

    // ---- self-loop edge ----
    process(ld_fp8<NV>(xlr + (size_t)node * STRIDE, laneoff), ea_l);

    // ---- real edges, batches of 64, unroll-4 with 4 slots in flight ----
    int cnt = end - start;
    for (int b0 = 0; b0 < cnt; b0 += 64) {
        int rem = imin(64, cnt - b0);
        int idx = start + b0 + lane;
        int idxc = imin(idx, end - 1);
        int2 pv = spk[idxc];

        auto rl = [&](int j) {
            int s = __builtin_amdgcn_readlane(pv.x, j);
            return ld_fp8<NV>(xlr + (size_t)s * STRIDE, laneoff);
        };
        auto rw = [&](int j) {
            return __int_as_float(__builtin_amdgcn_readlane(pv.y, j));
        };

        int rc = rem - 1;
        unsigned int X0 = rl(0),           X1 = rl(imin(1, rc)),
                     X2 = rl(imin(2, rc)), X3 = rl(imin(3, rc));
        float W0 = rw(0),            W1 = rw(imin(1, rc)),
              W2 = rw(imin(2, rc)),  W3 = rw(imin(3, rc));

        int j = 0;
        for (; j + 4 <= rem; j += 4) {
            unsigned int Y0 = rl(imin(j + 4, rc)), Y1 = rl(imin(j + 5, rc)),
                         Y2 = rl(imin(j + 6, rc)), Y3 = rl(imin(j + 7, rc));
            float U0 = rw(imin(j + 4, rc)), U1 = rw(imin(j + 5, rc)),
                  U2 = rw(imin(j + 6, rc)), U3 = rw(imin(j + 7, rc));
            process(X0, W0); process(X1, W1); process(X2, W2); process(X3, W3);
            X0 = Y0; X1 = Y1; X2 = Y2; X3 = Y3;
            W0 = U0; W1 = U1; W2 = U2; W3 = U3;
        }
        if (j < rem) {
            process(X0, W0);
            if (j + 1 < rem) {
                process(X1, W1);
                if (j + 2 < rem) process(X2, W2);
            }
        }
    }

    float inv = 1.0f / (l + 1e-16f);
    float b_r[NV];
    ld_row<NV>(b_r, bias + laneoff);
    float v[NV];
#pragma unroll
    for (int j = 0; j < NV; ++j) v[j] = fmaxf(o[j] * inv + b_r[j], 0.0f);

    if constexpr (OUT_MODE == 0) {
        // dense bf16 rows (h1)
        unsigned short* op = (unsigned short*)out + (size_t)node * HC + laneoff;
        if constexpr (NV == 4) {
            uint2 t;
            t.x = f2bf(v[0]) | (f2bf(v[1]) << 16);
            t.y = f2bf(v[2]) | (f2bf(v[3]) << 16);
            *(uint2*)op = t;
        } else {
            *(unsigned int*)op = f2bf(v[0]) | (f2bf(v[1]) << 16);
        }
    } else {
        // fused pooling: accumulate relu'd row into partial slot
        float* pacc = (float*)out + (size_t)(blockIdx.x & 255) * 128 + laneoff;
#pragma unroll
        for (int j = 0; j < NV; ++j) atomicAdd(&pacc[j], v[j]);
    }
}

// ---------------------------------------------------------------------------
// finish pooling, softmax over 128, sigmoid(alpha). 1024 threads.
// ---------------------------------------------------------------------------
__global__ void __launch_bounds__(1024)
pool_final(const float* __restrict__ partial, int nb,
           const float* __restrict__ alpha_in,
           float* __restrict__ out, int n) {
    __shared__ float acc[8][128];
    __shared__ float red[4];
    int t = threadIdx.x & 127;        // column
    int g = threadIdx.x >> 7;         // group 0..7
    float s = 0.0f;
    for (int b = g; b < nb; b += 8) s += partial[b * 128 + t];
    acc[g][t] = s;
    __syncthreads();
    if (threadIdx.x < 128) {
        float tot = 0.0f;
#pragma unroll
        for (int k = 0; k < 8; ++k) tot += acc[k][t];
        float mean = tot / (float)n;
        float mx = mean;
#pragma unroll
        for (int off = 32; off > 0; off >>= 1) mx = fmaxf(mx, __shfl_xor(mx, off, 64));
        if ((t & 63) == 0) red[t >> 6] = mx;
        __syncthreads();
        mx = fmaxf(red[0], red[1]);
        float ex = __expf(mean - mx);
        float sm = ex;
#pragma unroll
        for (int off = 32; off > 0; off >>= 1) sm += __shfl_xor(sm, off, 64);
        if ((t & 63) == 0) red[2 + (t >> 6)] = sm;
        __syncthreads();
        sm = red[2] + red[3];
        out[t] = ex / sm;
        if (t == 0) out[128] = 1.0f / (1.0f + __expf(-alpha_in[0]));
    }
}

// ---------------------------------------------------------------------------
extern "C" void kernel_launch(void* const* d_in, const int* in_sizes, int n_in,
                              void* d_out, int out_size, void* d_ws, size_t ws_size,
                              hipStream_t stream) {
    const float* x    = (const float*)d_in[0];
    const int*   ei   = (const int*)d_in[1];
    const float* ea   = (const float*)d_in[2];
    const float* W1l  = (const float*)d_in[3];
    const float* b1l  = (const float*)d_in[4];
    const float* W1r  = (const float*)d_in[5];
    const float* b1r  = (const float*)d_in[6];
    const float* We1  = (const float*)d_in[7];
    const float* att1 = (const float*)d_in[8];
    const float* bias1= (const float*)d_in[9];
    const float* W2l  = (const float*)d_in[10];
    const float* b2l  = (const float*)d_in[11];
    const float* W2r  = (const float*)d_in[12];
    const float* b2r  = (const float*)d_in[13];
    const float* We2  = (const float*)d_in[14];
    const float* att2 = (const float*)d_in[15];
    const float* bias2= (const float*)d_in[16];
    const float* alpha= (const float*)d_in[17];
    float* out = (float*)d_out;

    const int F = 128, HC1 = 256, HC2 = 128;
    const int n = in_sizes[0] / F;       // 20000
    const int E = in_sizes[1] / 2;       // 640000
    const int B = (n + 1023) / 1024;     // scan blocks

    char* ws = (char*)d_ws;
    size_t off = 0;
    auto alloc = [&](size_t bytes) { size_t p = off; off += (bytes + 255) & ~(size_t)255; return p; };

    unsigned long long* hist = (unsigned long long*)(ws + alloc((size_t)n * 8 * 8));  // padded x8
    int*   row_ptr = (int*)  (ws + alloc((size_t)(n + 1) * 4));
    int*   wptr    = (int*)  (ws + alloc((size_t)n * 16 * 4));                        // padded x16
    float* ea_loop = (float*)(ws + alloc((size_t)n * 4));
    int*   bsum    = (int*)  (ws + alloc(64 * 4));
    int2*  spk     = (int2*) (ws + alloc((size_t)E * 8));
    unsigned short* xb   = (unsigned short*)(ws + alloc((size_t)n * F * 2));
    unsigned short* Wt1  = (unsigned short*)(ws + alloc((size_t)F * (2 * HC1) * 2));
    unsigned short* Wt2  = (unsigned short*)(ws + alloc((size_t)HC1 * (2 * HC2) * 2));
    float* b1cat   = (float*)(ws + alloc((size_t)2 * HC1 * 4));
    float* b2cat   = (float*)(ws + alloc((size_t)2 * HC2 * 4));
    unsigned char* xlr1 = (unsigned char*)(ws + alloc((size_t)n * 2 * HC1));   // fp8
    unsigned short* h1  = (unsigned short*)(ws + alloc((size_t)n * HC1 * 2));  // bf16
    float* partial = (float*)(ws + alloc((size_t)256 * 128 * 4));
    unsigned char* xlr2 = xlr1;   // layer-2 fp8 projections alias layer-1 buffer
    const int NB_SLOTS = 256;

    (void)hipMemsetAsync(hist, 0, (size_t)n * 8 * 8, stream);
    (void)hipMemsetAsync(partial, 0, (size_t)NB_SLOTS * 128 * 4, stream);

    int tb = 256;
    {
        int nF4  = n * F / 4;
        int WTOT = 2 * F * HC1 + 2 * HC1 * HC2 + 2 * HC1 + 2 * HC2;
        int total = E + nF4 + WTOT;
        fused_prep<<<(total + tb - 1) / tb, tb, 0, stream>>>(
            ei, ea, hist, E, x, xb, nF4,
            W1l, W1r, W2l, W2r, b1l, b1r, b2l, b2r,
            Wt1, Wt2, b1cat, b2cat, F, HC1, HC2);
    }
    scan_a<<<B, 256, 0, stream>>>(hist, bsum, n);
    scan_b<<<1, 64, 0, stream>>>(bsum, row_ptr, B, n);
    scan_c<<<B, 256, 0, stream>>>(hist, bsum, row_ptr, wptr, ea_loop, n);
    edge_scatter<<<(E + tb - 1) / tb, tb, 0, stream>>>(ei, ea, wptr, spk, E);

    // layer 1: merged GEMM [n,128]@[128,512] -> xlr1 (fp8, xl|xr rows)
    {
        dim3 grid((n + 63) / 64, (2 * HC1) / 64);
        gemm_bf16<true><<<grid, 256, 0, stream>>>(xb, Wt1, b1cat, xlr1, n, 2 * HC1, F);
    }
    gat_agg<256, 512, 32, 0><<<(n + 3) / 4, 256, 0, stream>>>(
        xlr1, We1, att1, bias1, row_ptr, spk, ea_loop, h1, n);

    // layer 2: merged GEMM [n,256]@[256,256] -> xlr2 (fp8)
    {
        dim3 grid((n + 63) / 64, (2 * HC2) / 64);
        gemm_bf16<true><<<grid, 256, 0, stream>>>(h1, Wt2, b2cat, xlr2, n, 2 * HC2, HC1);
    }
    // layer-2 gat with fused pooling (writes partial, skips h2)
    gat_agg<128, 256, 128, 1><<<(n + 3) / 4, 256, 0, stream>>>(
        xlr2, We2, att2, bias2, row_ptr, spk, ea_loop, partial, n);

    pool_final<<<1, 1024, 0, stream>>>(partial, NB_SLOTS, alpha, out, n);
}

// Round 15
// 275.183 us; speedup vs baseline: 1.1698x; 1.0161x over previous
//
#include <hip/hip_runtime.h>
#include <math.h>

#define NEG_SLOPE 0.2f
#define LOG2E 1.4426950408889634f

typedef __attribute__((ext_vector_type(8))) short short8;   // 8 bf16 (4 VGPRs)
typedef __attribute__((ext_vector_type(4))) float f32x4;
typedef __attribute__((ext_vector_type(2))) float v2f;

__device__ __forceinline__ int imin(int a, int b) { return a < b ? a : b; }

__device__ __forceinline__ unsigned int f2bf(float f) {
    unsigned int u = __float_as_uint(f);
    return (u + 0x7fffu + ((u >> 16) & 1u)) >> 16;   // RNE
}
__device__ __forceinline__ float fast_exp2(float x) {
#if __has_builtin(__builtin_amdgcn_exp2f)
    return __builtin_amdgcn_exp2f(x);
#else
    return exp2f(x);
#endif
}
// fp8 (OCP e4m3 on gfx950) hardware pack/unpack
__device__ __forceinline__ unsigned char f2fp8(float v) {
    return (unsigned char)(__builtin_amdgcn_cvt_pk_fp8_f32(v, v, 0, false) & 0xff);
}
template <int CTRL>
__device__ __forceinline__ float dpp_add(float v) {
    int t = __builtin_amdgcn_update_dpp(0, __float_as_int(v), CTRL, 0xF, 0xF, true);
    return v + __int_as_float(t);
}

// ---------------------------------------------------------------------------
// Fused prep kernel: three disjoint index ranges in one launch.
//  [0, E)            : packed histogram (64-bit atomic, 64B-padded slots)
//  [E, E+nF4)        : x fp32 -> bf16 (vec4)
//  [E+nF4, ..+WTOT)  : weight transposes -> bf16 + bias concats
// ---------------------------------------------------------------------------
__global__ void fused_prep(const int* __restrict__ ei, const float* __restrict__ ea,
                           unsigned long long* __restrict__ hist, int E,
                           const float* __restrict__ x, unsigned short* __restrict__ xb, int nF4,
                           const float* __restrict__ W1l, const float* __restrict__ W1r,
                           const float* __restrict__ W2l, const float* __restrict__ W2r,
                           const float* __restrict__ b1l, const float* __restrict__ b1r,
                           const float* __restrict__ b2l, const float* __restrict__ b2r,
                           unsigned short* __restrict__ Wt1, unsigned short* __restrict__ Wt2,
                           float* __restrict__ b1cat, float* __restrict__ b2cat,
                           int F, int HC1, int HC2) {
    int i = blockIdx.x * blockDim.x + threadIdx.x;
    if (i < E) {
        int d = ei[E + i];
        long long fx = (long long)__float2int_rn(ea[i] * 65536.0f);
        unsigned long long v = ((unsigned long long)fx << 32) | 1ull;
        atomicAdd(&hist[(size_t)d * 8], v);
        return;
    }
    int j = i - E;
    if (j < nF4) {
        float4 v = ((const float4*)x)[j];
        uint2 r;
        r.x = f2bf(v.x) | (f2bf(v.y) << 16);
        r.y = f2bf(v.z) | (f2bf(v.w) << 16);
        ((uint2*)xb)[j] = r;
        return;
    }
    int k = j - nF4;
    int S1 = F * HC1, S2 = HC1 * HC2;
    if (k < S1) {
        int kk = k / HC1, nn = k - kk * HC1;
        Wt1[(size_t)nn * F + kk] = (unsigned short)f2bf(W1l[k]);
    } else if (k < 2 * S1) {
        int m = k - S1;
        int kk = m / HC1, nn = m - kk * HC1;
        Wt1[(size_t)(HC1 + nn) * F + kk] = (unsigned short)f2bf(W1r[m]);
    } else if (k < 2 * S1 + S2) {
        int m = k - 2 * S1;
        int kk = m / HC2, nn = m - kk * HC2;
        Wt2[(size_t)nn * HC1 + kk] = (unsigned short)f2bf(W2l[m]);
    } else if (k < 2 * S1 + 2 * S2) {
        int m = k - 2 * S1 - S2;
        int kk = m / HC2, nn = m - kk * HC2;
        Wt2[(size_t)(HC2 + nn) * HC1 + kk] = (unsigned short)f2bf(W2r[m]);
    } else if (k < 2 * S1 + 2 * S2 + 2 * HC1) {
        int m = k - 2 * S1 - 2 * S2;
        b1cat[m] = (m < HC1) ? b1l[m] : b1r[m - HC1];
    } else if (k < 2 * S1 + 2 * S2 + 2 * HC1 + 2 * HC2) {
        int m = k - 2 * S1 - 2 * S2 - 2 * HC1;
        b2cat[m] = (m < HC2) ? b2l[m] : b2r[m - HC2];
    }
}

// ---------------------------------------------------------------------------
// 2-phase parallel scan over hist (padded stride 8): scan_a computes raw
// block sums; scan_c derives its own prefix from bsum in-wave (scan_b folded).
// ---------------------------------------------------------------------------
__global__ void scan_a(const unsigned long long* __restrict__ hist, int* __restrict__ bsum, int n) {
    __shared__ int wred[4];
    int base = blockIdx.x * 1024;
    int tid = threadIdx.x;
    int s = 0;
#pragma unroll
    for (int k = 0; k < 4; ++k) {
        int i = base + tid + k * 256;
        if (i < n) s += (int)(hist[(size_t)i * 8] & 0xffffffffull);
    }
#pragma unroll
    for (int off = 32; off > 0; off >>= 1) s += __shfl_xor(s, off, 64);
    if ((tid & 63) == 0) wred[tid >> 6] = s;
    __syncthreads();
    if (tid == 0) bsum[blockIdx.x] = wred[0] + wred[1] + wred[2] + wred[3];
}

__global__ void scan_c(const unsigned long long* __restrict__ hist,
                       const int* __restrict__ bsum, int* __restrict__ row_ptr,
                       int* __restrict__ wptr_pad, float* __restrict__ ea_loop,
                       int n, int B) {
    __shared__ int wtot[4];
    __shared__ int sh_base;
    int tid = threadIdx.x;
    int wid = tid >> 6, lane = tid & 63;
    int i0 = blockIdx.x * 1024 + tid * 4;
    int dcnt[4]; float esum[4];
#pragma unroll
    for (int k = 0; k < 4; ++k) {
        if (i0 + k < n) {
            unsigned long long h = hist[(size_t)(i0 + k) * 8];
            dcnt[k] = (int)(h & 0xffffffffull);
            esum[k] = (float)((int)(h >> 32)) * (1.0f / 65536.0f);
        } else { dcnt[k] = 0; esum[k] = 0.0f; }
    }
    int tsum = dcnt[0] + dcnt[1] + dcnt[2] + dcnt[3];
    int s = tsum;
#pragma unroll
    for (int off = 1; off < 64; off <<= 1) {
        int t = __shfl_up(s, off, 64);
        if (lane >= off) s += t;
    }
    if (lane == 63) wtot[wid] = s;
    // wave 0: block prefix (sum of bsum[0..blockIdx)) and grand total
    if (tid < 64) {
        int v   = (tid < B) ? bsum[tid] : 0;
        int pre = (tid < (int)blockIdx.x) ? v : 0;
        int tot = v;
#pragma unroll
        for (int off = 32; off > 0; off >>= 1) {
            pre += __shfl_xor(pre, off, 64);
            tot += __shfl_xor(tot, off, 64);
        }
        if (tid == 0) {
            sh_base = pre;
            if (blockIdx.x == 0) row_ptr[n] = tot;
        }
    }
    __syncthreads();
    int wpre = 0;
#pragma unroll
    for (int k = 0; k < 4; ++k) if (k < wid) wpre += wtot[k];
    int pre = sh_base + wpre + (s - tsum);
    if (i0 < n) {
        int4 e;
        e.x = pre;
        e.y = pre + dcnt[0];
        e.z = e.y + dcnt[1];
        e.w = e.z + dcnt[2];
        *(int4*)(row_ptr + i0) = e;
        int ev[4] = { e.x, e.y, e.z, e.w };
        float4 el;
        el.x = esum[0] / fmaxf((float)dcnt[0], 1.0f);
        el.y = esum[1] / fmaxf((float)dcnt[1], 1.0f);
        el.z = esum[2] / fmaxf((float)dcnt[2], 1.0f);
        el.w = esum[3] / fmaxf((float)dcnt[3], 1.0f);
        *(float4*)(ea_loop + i0) = el;
#pragma unroll
        for (int k = 0; k < 4; ++k) wptr_pad[(size_t)(i0 + k) * 16] = ev[k];
    }
}

// ---------------------------------------------------------------------------
// scatter edges into CSR order; (src,w) packed as int2.
// ---------------------------------------------------------------------------
__global__ void edge_scatter(const int* __restrict__ ei, const float* __restrict__ ea,
                             int* __restrict__ wptr_pad, int2* __restrict__ spk, int E) {
    int e = blockIdx.x * blockDim.x + threadIdx.x;
    if (e < E) {
        int d = ei[E + e];
        int pos = atomicAdd(&wptr_pad[(size_t)d * 16], 1);
        spk[pos] = make_int2(ei[e], __float_as_int(ea[e]));
    }
}

// ---------------------------------------------------------------------------
// bf16 MFMA GEMM + bias (B pre-transposed), 64x64 tile, BK=32.
// OUT_FP8: epilogue packs to fp8 (e4m3, hardware RNE) else bf16.
// ---------------------------------------------------------------------------
template <bool OUT_FP8>
__global__ void __launch_bounds__(256)
gemm_bf16(const unsigned short* __restrict__ A, const unsigned short* __restrict__ Bt,
          const float* __restrict__ bias, void* __restrict__ Cv,
          int M, int N, int K) {
    __shared__ __attribute__((aligned(16))) unsigned short As[64 * 40];
    __shared__ __attribute__((aligned(16))) unsigned short Bs[64 * 40];
    int tid  = threadIdx.x;
    int wave = tid >> 6, lane = tid & 63;
    int m0 = blockIdx.x * 64, n0 = blockIdx.y * 64;
    int row = tid >> 2, kg = (tid & 3) * 8;

    f32x4 acc[4] = {};
    for (int kk = 0; kk < K; kk += 32) {
        int gm = m0 + row;
        uint4 av;
        if (gm < M) av = *(const uint4*)(A + (size_t)gm * K + kk + kg);
        else        av = make_uint4(0, 0, 0, 0);
        *(uint4*)&As[row * 40 + kg] = av;
        uint4 bv = *(const uint4*)(Bt + (size_t)(n0 + row) * K + kk + kg);
        *(uint4*)&Bs[row * 40 + kg] = bv;
        __syncthreads();
        short8 a = *(const short8*)&As[(wave * 16 + (lane & 15)) * 40 + (lane >> 4) * 8];
#pragma unroll
        for (int g = 0; g < 4; ++g) {
            short8 b = *(const short8*)&Bs[(g * 16 + (lane & 15)) * 40 + (lane >> 4) * 8];
            acc[g] = __builtin_amdgcn_mfma_f32_16x16x32_bf16(a, b, acc[g], 0, 0, 0);
        }
        __syncthreads();
    }
#pragma unroll
    for (int g = 0; g < 4; ++g) {
        int col = n0 + g * 16 + (lane & 15);
        float bs = bias[col];
#pragma unroll
        for (int r = 0; r < 4; ++r) {
            int grow = m0 + wave * 16 + (lane >> 4) * 4 + r;
            if (grow < M) {
                float val = acc[g][r] + bs;
                if constexpr (OUT_FP8) {
                    ((unsigned char*)Cv)[(size_t)grow * N + col] = f2fp8(val);
                } else {
                    ((unsigned short*)Cv)[(size_t)grow * N + col] = (unsigned short)f2bf(val);
                }
            }
        }
    }
}

// ---------------------------------------------------------------------------
// helpers for gat_agg (fp8 gather path)
// ---------------------------------------------------------------------------
template <int NV>
__device__ __forceinline__ void ld_row(float* r, const float* p) {
    if constexpr (NV == 4) {
        float4 t = *(const float4*)p;
        r[0] = t.x; r[1] = t.y; r[2] = t.z; r[3] = t.w;
    } else {
        float2 t = *(const float2*)p;
        r[0] = t.x; r[1] = t.y;
    }
}
template <int NV>
__device__ __forceinline__ unsigned int ld_fp8(const unsigned char* __restrict__ base, int off) {
    if constexpr (NV == 4) return *(const unsigned int*)(base + off);
    else                   return (unsigned int)(*(const unsigned short*)(base + off));
}
template <int NV>
__device__ __forceinline__ void unp_fp8(unsigned int u, float* xf) {
    v2f p0 = __builtin_amdgcn_cvt_pk_f32_fp8(u, false);
    xf[0] = p0.x; xf[1] = p0.y;
    if constexpr (NV == 4) {
        v2f p1 = __builtin_amdgcn_cvt_pk_f32_fp8(u, true);
        xf[2] = p1.x; xf[3] = p1.y;
    }
}
template <int G>
__device__ __forceinline__ float grp_reduce(float vs) {
    vs = dpp_add<0xB1>(vs);              // xor 1
    vs = dpp_add<0x4E>(vs);              // xor 2
    vs = dpp_add<0x141>(vs);             // xor 4 (row_half_mirror)
    if constexpr (G >= 16) vs = dpp_add<0x140>(vs);   // xor 8 (row_mirror)
    if constexpr (G >= 32) {             // xor 16
        int t = __builtin_amdgcn_ds_swizzle(__float_as_int(vs), 0x401F);
        vs += __int_as_float(t);
    }
    if constexpr (G >= 64) vs += __shfl_xor(vs, 32, 64);
    return vs;
}

// ---------------------------------------------------------------------------
// fused GATv2 gather(fp8) + score + softmax + aggregate + relu.
// xlr rows are fp8 bytes: xl at [0,HC), xr at [HC,2HC), row stride = STRIDE B.
// Mov-free double-buffered edge pipeline: two groups of 4 fp8 slots (1 VGPR
// each) alternate — process group A while loading group B, then swap.
// Main-loop loads skip index clamping (in-range when j+8<=rem).
// att coeffs pre-scaled by log2e; pr = native v_exp_f32.
// OUT_MODE 0: dense bf16 rows.  OUT_MODE 1: fused pooling into partial slots.
// ---------------------------------------------------------------------------
template <int HC, int STRIDE, int C, int OUT_MODE>
__global__ void __launch_bounds__(256)
gat_agg(const unsigned char* __restrict__ xlr,
        const float* __restrict__ We, const float* __restrict__ att,
        const float* __restrict__ bias,
        const int* __restrict__ row_ptr, const int2* __restrict__ spk,
        const float* __restrict__ ea_loop,
        void* __restrict__ out, int n) {
    constexpr int NV = HC / 64;      // channels per lane
    constexpr int G  = C / NV;       // lanes per head
    int wave = threadIdx.x >> 6;
    int lane = threadIdx.x & 63;
    int node = blockIdx.x * 4 + wave;
    if (node >= n) return;
    int laneoff = lane * NV;         // byte offset (1B/channel)

    float xr_r[NV], We_r[NV], att6[NV], att4[NV], o[NV];
    unp_fp8<NV>(ld_fp8<NV>(xlr + (size_t)node * STRIDE + HC, laneoff), xr_r);
    ld_row<NV>(We_r, We + laneoff);
    {
        float att_r[NV];
        ld_row<NV>(att_r, att + laneoff);
#pragma unroll
        for (int j = 0; j < NV; ++j) {
            att6[j] = 0.6f * LOG2E * att_r[j];
            att4[j] = 0.4f * LOG2E * att_r[j];
        }
    }
#pragma unroll
    for (int j = 0; j < NV; ++j) o[j] = 0.0f;

    int start = __builtin_amdgcn_readfirstlane(row_ptr[node]);
    int end   = __builtin_amdgcn_readfirstlane(row_ptr[node + 1]);
    float ea_l = ea_loop[node];
    float l = 0.0f;

    auto process = [&](unsigned int xu, float w) {
        float xf[NV];
        unp_fp8<NV>(xu, xf);
        float vs = 0.0f;
#pragma unroll
        for (int j = 0; j < NV; ++j) {
            float mm = xf[j] + fmaf(w, We_r[j], xr_r[j]);
            vs = fmaf(att6[j], mm, vs);
            vs = fmaf(att4[j], fabsf(mm), vs);
        }
        vs = grp_reduce<G>(vs);
        float pr = fast_exp2(vs);
        l += pr;
#pragma unroll
        for (int j = 0; j < NV; ++j) o[j] = fmaf(pr, xf[j], o[j]);
    };

    // ---- self-loop edge ----
    process(ld_fp8<NV>(xlr + (size_t)node * STRIDE, laneoff), ea_l);

    // ---- real edges: batches of 64, mov-free double-buffered pipeline ----
    int cnt = end - start;
    for (int b0 = 0; b0 < cnt; b0 += 64) {
        int rem = imin(64, cnt - b0);
        int idx = start + b0 + lane;
        int idxc = imin(idx, end - 1);
        int2 pv = spk[idxc];

        auto rl = [&](int j) {
            int s = __builtin_amdgcn_readlane(pv.x, j);
            return ld_fp8<NV>(xlr + (size_t)s * STRIDE, laneoff);
        };
        auto rw = [&](int j) {
            return __int_as_float(__builtin_amdgcn_readlane(pv.y, j));
        };

        int rc = rem - 1;
        unsigned int A0 = rl(0),           A1 = rl(imin(1, rc)),
                     A2 = rl(imin(2, rc)), A3 = rl(imin(3, rc));
        float Wa0 = rw(0),            Wa1 = rw(imin(1, rc)),
              Wa2 = rw(imin(2, rc)),  Wa3 = rw(imin(3, rc));

        int j = 0;
        for (; j + 8 <= rem; j += 8) {
            // load group B (edges j+4..j+7, guaranteed in range)
            unsigned int B0 = rl(j + 4), B1 = rl(j + 5), B2 = rl(j + 6), B3 = rl(j + 7);
            float Wb0 = rw(j + 4), Wb1 = rw(j + 5), Wb2 = rw(j + 6), Wb3 = rw(j + 7);
            // process group A (edges j..j+3)
            process(A0, Wa0); process(A1, Wa1); process(A2, Wa2); process(A3, Wa3);
            // reload group A (edges j+8..j+11, clamped)
            A0 = rl(imin(j + 8, rc));  A1 = rl(imin(j + 9, rc));
            A2 = rl(imin(j + 10, rc)); A3 = rl(imin(j + 11, rc));
            Wa0 = rw(imin(j + 8, rc));  Wa1 = rw(imin(j + 9, rc));
            Wa2 = rw(imin(j + 10, rc)); Wa3 = rw(imin(j + 11, rc));
            // process group B
            process(B0, Wb0); process(B1, Wb1); process(B2, Wb2); process(B3, Wb3);
        }
        // tail: group A holds edges j..j+3 (clamped); up to 7 remain
        int left = rem - j;
        if (left > 0) process(A0, Wa0);
        if (left > 1) process(A1, Wa1);
        if (left > 2) process(A2, Wa2);
        if (left > 3) process(A3, Wa3);
        for (int k = j + 4; k < rem; ++k) process(rl(k), rw(k));
    }

    float inv = 1.0f / (l + 1e-16f);
    float b_r[NV];
    ld_row<NV>(b_r, bias + laneoff);
    float v[NV];
#pragma unroll
    for (int j = 0; j < NV; ++j) v[j] = fmaxf(o[j] * inv + b_r[j], 0.0f);

    if constexpr (OUT_MODE == 0) {
        // dense bf16 rows (h1)
        unsigned short* op = (unsigned short*)out + (size_t)node * HC + laneoff;
        if constexpr (NV == 4) {
            uint2 t;
            t.x = f2bf(v[0]) | (f2bf(v[1]) << 16);
            t.y = f2bf(v[2]) | (f2bf(v[3]) << 16);
            *(uint2*)op = t;
        } else {
            *(unsigned int*)op = f2bf(v[0]) | (f2bf(v[1]) << 16);
        }
    } else {
        // fused pooling: accumulate relu'd row into partial slot
        float* pacc = (float*)out + (size_t)(blockIdx.x & 255) * 128 + laneoff;
#pragma unroll
        for (int j = 0; j < NV; ++j) atomicAdd(&pacc[j], v[j]);
    }
}

// ---------------------------------------------------------------------------
// finish pooling, softmax over 128, sigmoid(alpha). 1024 threads.
// ---------------------------------------------------------------------------
__global__ void __launch_bounds__(1024)
pool_final(const float* __restrict__ partial, int nb,
           const float* __restrict__ alpha_in,
           float* __restrict__ out, int n) {
    __shared__ float acc[8][128];
    __shared__ float red[4];
    int t = threadIdx.x & 127;        // column
    int g = threadIdx.x >> 7;         // group 0..7
    float s = 0.0f;
    for (int b = g; b < nb; b += 8) s += partial[b * 128 + t];
    acc[g][t] = s;
    __syncthreads();
    if (threadIdx.x < 128) {
        float tot = 0.0f;
#pragma unroll
        for (int k = 0; k < 8; ++k) tot += acc[k][t];
        float mean = tot / (float)n;
        float mx = mean;
#pragma unroll
        for (int off = 32; off > 0; off >>= 1) mx = fmaxf(mx, __shfl_xor(mx, off, 64));
        if ((t & 63) == 0) red[t >> 6] = mx;
        __syncthreads();
        mx = fmaxf(red[0], red[1]);
        float ex = __expf(mean - mx);
        float sm = ex;
#pragma unroll
        for (int off = 32; off > 0; off >>= 1) sm += __shfl_xor(sm, off, 64);
        if ((t & 63) == 0) red[2 + (t >> 6)] = sm;
        __syncthreads();
        sm = red[2] + red[3];
        out[t] = ex / sm;
        if (t == 0) out[128] = 1.0f / (1.0f + __expf(-alpha_in[0]));
    }
}

// ---------------------------------------------------------------------------
extern "C" void kernel_launch(void* const* d_in, const int* in_sizes, int n_in,
                              void* d_out, int out_size, void* d_ws, size_t ws_size,
                              hipStream_t stream) {
    const float* x    = (const float*)d_in[0];
    const int*   ei   = (const int*)d_in[1];
    const float* ea   = (const float*)d_in[2];
    const float* W1l  = (const float*)d_in[3];
    const float* b1l  = (const float*)d_in[4];
    const float* W1r  = (const float*)d_in[5];
    const float* b1r  = (const float*)d_in[6];
    const float* We1  = (const float*)d_in[7];
    const float* att1 = (const float*)d_in[8];
    const float* bias1= (const float*)d_in[9];
    const float* W2l  = (const float*)d_in[10];
    const float* b2l  = (const float*)d_in[11];
    const float* W2r  = (const float*)d_in[12];
    const float* b2r  = (const float*)d_in[13];
    const float* We2  = (const float*)d_in[14];
    const float* att2 = (const float*)d_in[15];
    const float* bias2= (const float*)d_in[16];
    const float* alpha= (const float*)d_in[17];
    float* out = (float*)d_out;

    const int F = 128, HC1 = 256, HC2 = 128;
    const int n = in_sizes[0] / F;       // 20000
    const int E = in_sizes[1] / 2;       // 640000
    const int B = (n + 1023) / 1024;     // scan blocks

    char* ws = (char*)d_ws;
    size_t off = 0;
    auto alloc = [&](size_t bytes) { size_t p = off; off += (bytes + 255) & ~(size_t)255; return p; };

    unsigned long long* hist = (unsigned long long*)(ws + alloc((size_t)n * 8 * 8));  // padded x8
    int*   row_ptr = (int*)  (ws + alloc((size_t)(n + 1) * 4));
    int*   wptr    = (int*)  (ws + alloc((size_t)n * 16 * 4));                        // padded x16
    float* ea_loop = (float*)(ws + alloc((size_t)n * 4));
    int*   bsum    = (int*)  (ws + alloc(64 * 4));
    int2*  spk     = (int2*) (ws + alloc((size_t)E * 8));
    unsigned short* xb   = (unsigned short*)(ws + alloc((size_t)n * F * 2));
    unsigned short* Wt1  = (unsigned short*)(ws + alloc((size_t)F * (2 * HC1) * 2));
    unsigned short* Wt2  = (unsigned short*)(ws + alloc((size_t)HC1 * (2 * HC2) * 2));
    float* b1cat   = (float*)(ws + alloc((size_t)2 * HC1 * 4));
    float* b2cat   = (float*)(ws + alloc((size_t)2 * HC2 * 4));
    unsigned char* xlr1 = (unsigned char*)(ws + alloc((size_t)n * 2 * HC1));   // fp8
    unsigned short* h1  = (unsigned short*)(ws + alloc((size_t)n * HC1 * 2));  // bf16
    float* partial = (float*)(ws + alloc((size_t)256 * 128 * 4));
    unsigned char* xlr2 = xlr1;   // layer-2 fp8 projections alias layer-1 buffer
    const int NB_SLOTS = 256;

    (void)hipMemsetAsync(hist, 0, (size_t)n * 8 * 8, stream);
    (void)hipMemsetAsync(partial, 0, (size_t)NB_SLOTS * 128 * 4, stream);

    int tb = 256;
    {
        int nF4  = n * F / 4;
        int WTOT = 2 * F * HC1 + 2 * HC1 * HC2 + 2 * HC1 + 2 * HC2;
        int total = E + nF4 + WTOT;
        fused_prep<<<(total + tb - 1) / tb, tb, 0, stream>>>(
            ei, ea, hist, E, x, xb, nF4,
            W1l, W1r, W2l, W2r, b1l, b1r, b2l, b2r,
            Wt1, Wt2, b1cat, b2cat, F, HC1, HC2);
    }
    scan_a<<<B, 256, 0, stream>>>(hist, bsum, n);
    scan_c<<<B, 256, 0, stream>>>(hist, bsum, row_ptr, wptr, ea_loop, n, B);
    edge_scatter<<<(E + tb - 1) / tb, tb, 0, stream>>>(ei, ea, wptr, spk, E);

    // layer 1: merged GEMM [n,128]@[128,512] -> xlr1 (fp8, xl|xr rows)
    {
        dim3 grid((n + 63) / 64, (2 * HC1) / 64);
        gemm_bf16<true><<<grid, 256, 0, stream>>>(xb, Wt1, b1cat, xlr1, n, 2 * HC1, F);
    }
    gat_agg<256, 512, 32, 0><<<(n + 3) / 4, 256, 0, stream>>>(
        xlr1, We1, att1, bias1, row_ptr, spk, ea_loop, h1, n);

    // layer 2: merged GEMM [n,256]@[256,256] -> xlr2 (fp8)
    {
        dim3 grid((n + 63) / 64, (2 * HC2) / 64);
        gemm_bf16<true><<<grid, 256, 0, stream>>>(h1, Wt2, b2cat, xlr2, n, 2 * HC2, HC1);
    }
    // layer-2 gat with fused pooling (writes partial, skips h2)
    gat_agg<128, 256, 128, 1><<<(n + 3) / 4, 256, 0, stream>>>(
        xlr2, We2, att2, bias2, row_ptr, spk, ea_loop, partial, n);

    pool_final<<<1, 1024, 0, stream>>>(partial, NB_SLOTS, alpha, out, n);
}